// Round 1
// baseline (101338.434 us; speedup 1.0000x reference)
//
#include <hip/hip_runtime.h>
#include <hip/hip_bf16.h>

// Dims (fixed by the reference)
#define SLEN 4096
#define CLEN 12
#define ECD  256
#define HCD  256
#define ED   1024
#define HD   1024
#define TD   64

__device__ __forceinline__ float sigmoidf_(float x) { return 1.f / (1.f + expf(-x)); }

// ---------------------------------------------------------------------------
// Char-level LSTM step GEMM: gates[s][r] = sum_k A[s][k]*B[r][k] + b_ih_c[r]+b_hh_c[r]
//   A[s][k] = (k<256) ? W_emb_char[char_idx[s][t]][k] : h_c[s][k-256]   (K=512)
//   B[r][k] = (k<256) ? W_ih_c[r][k]                  : W_hh_c[r][k-256]
// M=4096, N=1024, K=512. 64x64 tile, 256 threads, 4x4 per thread.
// ---------------------------------------------------------------------------
__global__ __launch_bounds__(256) void char_gemm(
    const int* __restrict__ char_idx, int t,
    const float* __restrict__ Wec,
    const float* __restrict__ Wihc, const float* __restrict__ Whhc,
    const float* __restrict__ bihc, const float* __restrict__ bhhc,
    const float* __restrict__ h_c, float* __restrict__ gates)
{
    __shared__ float As[16][65];
    __shared__ float Bs[16][65];
    __shared__ int   cidx[64];
    const int tid = threadIdx.x;
    const int m0 = blockIdx.x * 64;
    const int n0 = blockIdx.y * 64;
    if (tid < 64) cidx[tid] = char_idx[(m0 + tid) * CLEN + t];
    __syncthreads();

    float acc[4][4] = {};
    const int tm = tid >> 4, tn = tid & 15;

    for (int k0 = 0; k0 < 512; k0 += 16) {
        #pragma unroll
        for (int i = 0; i < 4; ++i) {
            int e = tid + i * 256;
            int k = e >> 6, m = e & 63;
            int kk = k0 + k;
            float v;
            if (kk < 256) v = Wec[cidx[m] * 256 + kk];
            else          v = h_c[(size_t)(m0 + m) * 256 + (kk - 256)];
            As[k][m] = v;
        }
        #pragma unroll
        for (int i = 0; i < 4; ++i) {
            int e = tid + i * 256;
            int k = e >> 6, n = e & 63;
            int kk = k0 + k;
            int r = n0 + n;
            float v;
            if (kk < 256) v = Wihc[r * 256 + kk];
            else          v = Whhc[r * 256 + (kk - 256)];
            Bs[k][n] = v;
        }
        __syncthreads();
        #pragma unroll
        for (int k = 0; k < 16; ++k) {
            float a[4], b[4];
            #pragma unroll
            for (int i = 0; i < 4; ++i) a[i] = As[k][tm * 4 + i];
            #pragma unroll
            for (int j = 0; j < 4; ++j) b[j] = Bs[k][tn * 4 + j];
            #pragma unroll
            for (int i = 0; i < 4; ++i)
                #pragma unroll
                for (int j = 0; j < 4; ++j) acc[i][j] += a[i] * b[j];
        }
        __syncthreads();
    }
    #pragma unroll
    for (int i = 0; i < 4; ++i) {
        int m = m0 + tm * 4 + i;
        #pragma unroll
        for (int j = 0; j < 4; ++j) {
            int r = n0 + tn * 4 + j;
            gates[(size_t)m * 1024 + r] = acc[i][j] + bihc[r] + bhhc[r];
        }
    }
}

// Elementwise char LSTM cell update (i,f,g,o gate order, chunks of 256)
__global__ __launch_bounds__(256) void char_cell(
    const float* __restrict__ gates, float* __restrict__ h, float* __restrict__ c)
{
    int idx = blockIdx.x * 256 + threadIdx.x;      // 4096*256
    int s = idx >> 8, u = idx & 255;
    const float* g = gates + (size_t)s * 1024;
    float ig = sigmoidf_(g[u]);
    float fg = sigmoidf_(g[256 + u]);
    float gg = tanhf(g[512 + u]);
    float og = sigmoidf_(g[768 + u]);
    float cn = fg * c[idx] + ig * gg;
    c[idx] = cn;
    h[idx] = og * tanhf(cn);
}

// ---------------------------------------------------------------------------
// Word-level input precompute GEMM:
//   precomp[t][r] = sum_k x[t][k]*W_ih[r][k] + b_ih[r] + b_hh[r]
//   x[t][k] = (k<1024) ? W_emb_word[word_idx[t]][k] : h_char[t][k-1024]  (K=1280)
// M=4096, N=4096, K=1280.
// ---------------------------------------------------------------------------
__global__ __launch_bounds__(256) void word_gemm(
    const int* __restrict__ word_idx,
    const float* __restrict__ Wemb,
    const float* __restrict__ h_char,
    const float* __restrict__ Wih,
    const float* __restrict__ bih, const float* __restrict__ bhh,
    float* __restrict__ precomp)
{
    __shared__ float As[16][65];
    __shared__ float Bs[16][65];
    __shared__ int   widx[64];
    const int tid = threadIdx.x;
    const int m0 = blockIdx.x * 64;
    const int n0 = blockIdx.y * 64;
    if (tid < 64) widx[tid] = word_idx[m0 + tid];
    __syncthreads();

    float acc[4][4] = {};
    const int tm = tid >> 4, tn = tid & 15;

    for (int k0 = 0; k0 < 1280; k0 += 16) {
        #pragma unroll
        for (int i = 0; i < 4; ++i) {
            int e = tid + i * 256;
            int k = e >> 6, m = e & 63;
            int kk = k0 + k;
            float v;
            if (kk < 1024) v = Wemb[(size_t)widx[m] * 1024 + kk];
            else           v = h_char[(size_t)(m0 + m) * 256 + (kk - 1024)];
            As[k][m] = v;
        }
        #pragma unroll
        for (int i = 0; i < 4; ++i) {
            int e = tid + i * 256;
            int k = e >> 6, n = e & 63;
            Bs[k][n] = Wih[(size_t)(n0 + n) * 1280 + (k0 + k)];
        }
        __syncthreads();
        #pragma unroll
        for (int k = 0; k < 16; ++k) {
            float a[4], b[4];
            #pragma unroll
            for (int i = 0; i < 4; ++i) a[i] = As[k][tm * 4 + i];
            #pragma unroll
            for (int j = 0; j < 4; ++j) b[j] = Bs[k][tn * 4 + j];
            #pragma unroll
            for (int i = 0; i < 4; ++i)
                #pragma unroll
                for (int j = 0; j < 4; ++j) acc[i][j] += a[i] * b[j];
        }
        __syncthreads();
    }
    #pragma unroll
    for (int i = 0; i < 4; ++i) {
        int m = m0 + tm * 4 + i;
        #pragma unroll
        for (int j = 0; j < 4; ++j) {
            int r = n0 + tn * 4 + j;
            precomp[(size_t)m * 4096 + r] = acc[i][j] + bih[r] + bhh[r];
        }
    }
}

// ---------------------------------------------------------------------------
// Word-level LSTM recurrence: persistent kernel, 256 WGs x 256 threads.
// WG w owns hidden units [w*4, w*4+4) -> 16 gate rows of W_hh (bf16 in LDS).
// Per step: device-wide flag barrier (release/acquire, agent scope), read h,
// GEMV rows, gate nonlinearity, publish h part + flag.
// ---------------------------------------------------------------------------
__global__ __launch_bounds__(256) void word_rec(
    const float* __restrict__ precomp, const float* __restrict__ W_hh,
    float* __restrict__ hs, float* hbuf, int* flags)
{
    const int w   = blockIdx.x;   // 0..255
    const int tid = threadIdx.x;  // 0..255
    const int row = tid >> 4;     // 0..15 local gate-row
    const int ks  = tid & 15;     // k-slice (strided by 16 to avoid LDS bank conflicts)
    const int gate = row >> 2, unit = row & 3;
    const int grow = gate * 1024 + w * 4 + unit;   // global gate row

    __shared__ __hip_bfloat16 Wl[16][1032];  // pad: row stride 2064B -> 4-bank offset
    __shared__ float h_lds[1024];
    __shared__ float gl[16];
    __shared__ float c_l[4];

    // Preload this WG's 16 rows of W_hh into LDS as bf16 (coalesced global reads)
    for (int e = tid; e < 16 * 1024; e += 256) {
        int rr = e >> 10, k = e & 1023;
        int gr = (rr >> 2) * 1024 + w * 4 + (rr & 3);
        Wl[rr][k] = __float2bfloat16(W_hh[(size_t)gr * 1024 + k]);
    }
    if (tid < 4) c_l[tid] = 0.f;
    __syncthreads();

    for (int t = 0; t < SLEN; ++t) {
        if (t > 0) {
            // Wait until every WG has published h_{t-1}
            while (__hip_atomic_load(&flags[tid], __ATOMIC_ACQUIRE,
                                     __HIP_MEMORY_SCOPE_AGENT) < t) { }
            float* hb = hbuf + ((t - 1) & 1) * 1024;
            #pragma unroll
            for (int j = 0; j < 4; ++j)
                h_lds[tid * 4 + j] = __hip_atomic_load(&hb[tid * 4 + j],
                        __ATOMIC_RELAXED, __HIP_MEMORY_SCOPE_AGENT);
        } else {
            #pragma unroll
            for (int j = 0; j < 4; ++j) h_lds[tid * 4 + j] = 0.f;
        }
        __syncthreads();

        // 16 dot products of length 1024, 16 lanes each (k = ks + 16*j)
        float acc = 0.f;
        #pragma unroll 8
        for (int j = 0; j < 64; ++j) {
            int k = ks + (j << 4);
            acc += __bfloat162float(Wl[row][k]) * h_lds[k];
        }
        acc += __shfl_xor(acc, 1);
        acc += __shfl_xor(acc, 2);
        acc += __shfl_xor(acc, 4);
        acc += __shfl_xor(acc, 8);
        if (ks == 0) gl[row] = acc + precomp[(size_t)t * 4096 + grow];
        __syncthreads();

        if (tid < 4) {
            int u = tid;
            float ig = sigmoidf_(gl[u]);
            float fg = sigmoidf_(gl[4 + u]);
            float gg = tanhf(gl[8 + u]);
            float og = sigmoidf_(gl[12 + u]);
            float cn = fg * c_l[u] + ig * gg;
            c_l[u] = cn;
            float h = og * tanhf(cn);
            hs[(size_t)t * 1024 + w * 4 + u] = h;
            __hip_atomic_store(&hbuf[(t & 1) * 1024 + w * 4 + u], h,
                               __ATOMIC_RELAXED, __HIP_MEMORY_SCOPE_AGENT);
        }
        __syncthreads();
        if (tid == 0)
            __hip_atomic_store(&flags[w], t + 1,
                               __ATOMIC_RELEASE, __HIP_MEMORY_SCOPE_AGENT);
    }
}

// ---------------------------------------------------------------------------
// Tag projection + log_softmax: one WG per sequence position.
// ---------------------------------------------------------------------------
__global__ __launch_bounds__(256) void tag_kernel(
    const float* __restrict__ hs, const float* __restrict__ Wtag,
    const float* __restrict__ btag, float* __restrict__ out)
{
    const int t = blockIdx.x;
    __shared__ float hrow[1024];
    __shared__ float logit[64];
    const int tid = threadIdx.x;
    for (int j = tid; j < 1024; j += 256) hrow[j] = hs[(size_t)t * 1024 + j];
    __syncthreads();
    const int j = tid >> 2, p = tid & 3;   // 4 lanes per tag
    float acc = 0.f;
    for (int k = p * 256; k < p * 256 + 256; ++k)
        acc += hrow[k] * Wtag[(size_t)j * 1024 + k];
    acc += __shfl_xor(acc, 1);
    acc += __shfl_xor(acc, 2);
    if (p == 0) logit[j] = acc + btag[j];
    __syncthreads();
    if (tid < 64) {
        float l = logit[tid];
        float m = l;
        #pragma unroll
        for (int off = 1; off < 64; off <<= 1) m = fmaxf(m, __shfl_xor(m, off));
        float e = expf(l - m);
        float ssum = e;
        #pragma unroll
        for (int off = 1; off < 64; off <<= 1) ssum += __shfl_xor(ssum, off);
        out[(size_t)t * 64 + tid] = l - m - logf(ssum);
    }
}

// ---------------------------------------------------------------------------
extern "C" void kernel_launch(void* const* d_in, const int* in_sizes, int n_in,
                              void* d_out, int out_size, void* d_ws, size_t ws_size,
                              hipStream_t stream)
{
    const int*   char_idx = (const int*)  d_in[0];
    const int*   word_idx = (const int*)  d_in[1];
    const float* Wemb     = (const float*)d_in[2];
    const float* Wec      = (const float*)d_in[3];
    const float* Wihc     = (const float*)d_in[4];
    const float* Whhc     = (const float*)d_in[5];
    const float* bihc     = (const float*)d_in[6];
    const float* bhhc     = (const float*)d_in[7];
    const float* Wih      = (const float*)d_in[8];
    const float* Whh      = (const float*)d_in[9];
    const float* bih      = (const float*)d_in[10];
    const float* bhh      = (const float*)d_in[11];
    const float* Wtag     = (const float*)d_in[12];
    const float* btag     = (const float*)d_in[13];
    float* out = (float*)d_out;

    // Workspace layout (fp32 elements). Total ~109.1 MB required.
    float* ws      = (float*)d_ws;
    float* h_c     = ws;                               // 4096*256
    float* c_c     = h_c   + (size_t)SLEN * HCD;       // 4096*256
    float* gatesc  = c_c   + (size_t)SLEN * HCD;       // 4096*1024
    float* precomp = gatesc + (size_t)SLEN * 1024;     // 4096*4096
    float* hs      = precomp + (size_t)SLEN * 4096;    // 4096*1024
    float* hbuf    = hs    + (size_t)SLEN * HD;        // 2*1024
    int*   flags   = (int*)(hbuf + 2048);              // 256

    hipMemsetAsync(h_c,   0, (size_t)SLEN * HCD * sizeof(float), stream);
    hipMemsetAsync(c_c,   0, (size_t)SLEN * HCD * sizeof(float), stream);
    hipMemsetAsync(flags, 0, 256 * sizeof(int), stream);

    // Char-level LSTM: 12 sequential steps, batched over all 4096 words
    for (int t = 0; t < CLEN; ++t) {
        char_gemm<<<dim3(SLEN / 64, 1024 / 64), 256, 0, stream>>>(
            char_idx, t, Wec, Wihc, Whhc, bihc, bhhc, h_c, gatesc);
        char_cell<<<(SLEN * HCD) / 256, 256, 0, stream>>>(gatesc, h_c, c_c);
    }

    // Word-level input projection for all timesteps (h_c now holds h_char)
    word_gemm<<<dim3(SLEN / 64, 4096 / 64), 256, 0, stream>>>(
        word_idx, Wemb, h_c, Wih, bih, bhh, precomp);

    // Sequential word-level LSTM recurrence (persistent, device-wide barrier)
    word_rec<<<256, 256, 0, stream>>>(precomp, Whh, hs, hbuf, flags);

    // Tag projection + log_softmax
    tag_kernel<<<SLEN, 256, 0, stream>>>(hs, Wtag, btag, out);
}

// Round 2
// 19994.493 us; speedup vs baseline: 5.0683x; 5.0683x over previous
//
#include <hip/hip_runtime.h>
#include <hip/hip_bf16.h>

// Dims (fixed by the reference)
#define SLEN 4096
#define CLEN 12
#define ECD  256
#define HCD  256
#define ED   1024
#define HD   1024
#define TD   64

__device__ __forceinline__ float sigmoidf_(float x) { return 1.f / (1.f + expf(-x)); }

// round-to-nearest-even f32 -> bf16 bits
__device__ __forceinline__ unsigned f32_to_bf16_bits(float f) {
    unsigned u = __float_as_uint(f);
    return (u + 0x7FFFu + ((u >> 16) & 1u)) >> 16;
}
__device__ __forceinline__ float bf16_bits_to_f32(unsigned b) {
    return __uint_as_float(b << 16);
}

// ---------------------------------------------------------------------------
// Char-level LSTM step GEMM (unchanged from R1): M=4096, N=1024, K=512.
// ---------------------------------------------------------------------------
__global__ __launch_bounds__(256) void char_gemm(
    const int* __restrict__ char_idx, int t,
    const float* __restrict__ Wec,
    const float* __restrict__ Wihc, const float* __restrict__ Whhc,
    const float* __restrict__ bihc, const float* __restrict__ bhhc,
    const float* __restrict__ h_c, float* __restrict__ gates)
{
    __shared__ float As[16][65];
    __shared__ float Bs[16][65];
    __shared__ int   cidx[64];
    const int tid = threadIdx.x;
    const int m0 = blockIdx.x * 64;
    const int n0 = blockIdx.y * 64;
    if (tid < 64) cidx[tid] = char_idx[(m0 + tid) * CLEN + t];
    __syncthreads();

    float acc[4][4] = {};
    const int tm = tid >> 4, tn = tid & 15;

    for (int k0 = 0; k0 < 512; k0 += 16) {
        #pragma unroll
        for (int i = 0; i < 4; ++i) {
            int e = tid + i * 256;
            int k = e >> 6, m = e & 63;
            int kk = k0 + k;
            float v;
            if (kk < 256) v = Wec[cidx[m] * 256 + kk];
            else          v = h_c[(size_t)(m0 + m) * 256 + (kk - 256)];
            As[k][m] = v;
        }
        #pragma unroll
        for (int i = 0; i < 4; ++i) {
            int e = tid + i * 256;
            int k = e >> 6, n = e & 63;
            int kk = k0 + k;
            int r = n0 + n;
            float v;
            if (kk < 256) v = Wihc[r * 256 + kk];
            else          v = Whhc[r * 256 + (kk - 256)];
            Bs[k][n] = v;
        }
        __syncthreads();
        #pragma unroll
        for (int k = 0; k < 16; ++k) {
            float a[4], b[4];
            #pragma unroll
            for (int i = 0; i < 4; ++i) a[i] = As[k][tm * 4 + i];
            #pragma unroll
            for (int j = 0; j < 4; ++j) b[j] = Bs[k][tn * 4 + j];
            #pragma unroll
            for (int i = 0; i < 4; ++i)
                #pragma unroll
                for (int j = 0; j < 4; ++j) acc[i][j] += a[i] * b[j];
        }
        __syncthreads();
    }
    #pragma unroll
    for (int i = 0; i < 4; ++i) {
        int m = m0 + tm * 4 + i;
        #pragma unroll
        for (int j = 0; j < 4; ++j) {
            int r = n0 + tn * 4 + j;
            gates[(size_t)m * 1024 + r] = acc[i][j] + bihc[r] + bhhc[r];
        }
    }
}

// Elementwise char LSTM cell update
__global__ __launch_bounds__(256) void char_cell(
    const float* __restrict__ gates, float* __restrict__ h, float* __restrict__ c)
{
    int idx = blockIdx.x * 256 + threadIdx.x;      // 4096*256
    int s = idx >> 8, u = idx & 255;
    const float* g = gates + (size_t)s * 1024;
    float ig = sigmoidf_(g[u]);
    float fg = sigmoidf_(g[256 + u]);
    float gg = tanhf(g[512 + u]);
    float og = sigmoidf_(g[768 + u]);
    float cn = fg * c[idx] + ig * gg;
    c[idx] = cn;
    h[idx] = og * tanhf(cn);
}

// ---------------------------------------------------------------------------
// Word-level input precompute GEMM (unchanged): M=4096, N=4096, K=1280.
// ---------------------------------------------------------------------------
__global__ __launch_bounds__(256) void word_gemm(
    const int* __restrict__ word_idx,
    const float* __restrict__ Wemb,
    const float* __restrict__ h_char,
    const float* __restrict__ Wih,
    const float* __restrict__ bih, const float* __restrict__ bhh,
    float* __restrict__ precomp)
{
    __shared__ float As[16][65];
    __shared__ float Bs[16][65];
    __shared__ int   widx[64];
    const int tid = threadIdx.x;
    const int m0 = blockIdx.x * 64;
    const int n0 = blockIdx.y * 64;
    if (tid < 64) widx[tid] = word_idx[m0 + tid];
    __syncthreads();

    float acc[4][4] = {};
    const int tm = tid >> 4, tn = tid & 15;

    for (int k0 = 0; k0 < 1280; k0 += 16) {
        #pragma unroll
        for (int i = 0; i < 4; ++i) {
            int e = tid + i * 256;
            int k = e >> 6, m = e & 63;
            int kk = k0 + k;
            float v;
            if (kk < 1024) v = Wemb[(size_t)widx[m] * 1024 + kk];
            else           v = h_char[(size_t)(m0 + m) * 256 + (kk - 1024)];
            As[k][m] = v;
        }
        #pragma unroll
        for (int i = 0; i < 4; ++i) {
            int e = tid + i * 256;
            int k = e >> 6, n = e & 63;
            Bs[k][n] = Wih[(size_t)(n0 + n) * 1280 + (k0 + k)];
        }
        __syncthreads();
        #pragma unroll
        for (int k = 0; k < 16; ++k) {
            float a[4], b[4];
            #pragma unroll
            for (int i = 0; i < 4; ++i) a[i] = As[k][tm * 4 + i];
            #pragma unroll
            for (int j = 0; j < 4; ++j) b[j] = Bs[k][tn * 4 + j];
            #pragma unroll
            for (int i = 0; i < 4; ++i)
                #pragma unroll
                for (int j = 0; j < 4; ++j) acc[i][j] += a[i] * b[j];
        }
        __syncthreads();
    }
    #pragma unroll
    for (int i = 0; i < 4; ++i) {
        int m = m0 + tm * 4 + i;
        #pragma unroll
        for (int j = 0; j < 4; ++j) {
            int r = n0 + tn * 4 + j;
            precomp[(size_t)m * 4096 + r] = acc[i][j] + bih[r] + bhh[r];
        }
    }
}

// ---------------------------------------------------------------------------
// Word-level LSTM recurrence v2: fence-free tagged handoff.
//
// 256 WGs x 256 threads. WG w owns hidden units [4w, 4w+4).
// Thread tid holds W_hh[16 gate rows][k=4*tid..4*tid+4) in REGISTERS (64 VGPR).
// h is exchanged as u32 words: (step_tag << 16) | bf16(h). Value+tag share one
// atomic word -> no fences, no flags, no acquire invalidates. Double-buffered
// by step parity (WG skew is <=1 step, so overwrite is safe). Consumers poll
// with relaxed agent-scope loads; tag match guarantees the value is current.
// ---------------------------------------------------------------------------
__global__ __launch_bounds__(256) void word_rec(
    const float* __restrict__ precomp, const float* __restrict__ W_hh,
    float* __restrict__ hs, unsigned int* hbuf)
{
    const int w    = blockIdx.x;   // 0..255
    const int tid  = threadIdx.x;  // 0..255
    const int lane = tid & 63;
    const int wv   = tid >> 6;     // wave 0..3

    // --- load this thread's W_hh slice into registers (fully coalesced) ---
    float Wreg[16][4];
    #pragma unroll
    for (int r = 0; r < 16; ++r) {
        const int grow = (r >> 2) * 1024 + w * 4 + (r & 3);   // gate-major row
        const float4 v = *reinterpret_cast<const float4*>(
            &W_hh[(size_t)grow * 1024 + tid * 4]);
        Wreg[r][0] = v.x; Wreg[r][1] = v.y; Wreg[r][2] = v.z; Wreg[r][3] = v.w;
    }

    __shared__ float ws_part[4][16];
    float c_reg = 0.f;  // cell state: valid in wave 0, lanes 0..3

    const int myrow_g = (wv == 0 && lane < 16)
                      ? ((lane >> 2) * 1024 + w * 4 + (lane & 3)) : 0;

    for (int t = 0; t < SLEN; ++t) {
        // prefetch this step's precomp contribution (hides HBM latency under poll)
        float pre = 0.f;
        if (wv == 0 && lane < 16) pre = precomp[(size_t)t * 4096 + myrow_g];

        // --- acquire h_{t-1} for my k-slice (4 tagged words) ---
        float h0, h1, h2, h3;
        if (t > 0) {
            const unsigned tag = (unsigned)(t - 1);
            unsigned int* src = hbuf + ((t - 1) & 1) * 1024 + tid * 4;
            unsigned a, b, c2, d;
            for (;;) {
                a  = __hip_atomic_load(src + 0, __ATOMIC_RELAXED, __HIP_MEMORY_SCOPE_AGENT);
                b  = __hip_atomic_load(src + 1, __ATOMIC_RELAXED, __HIP_MEMORY_SCOPE_AGENT);
                c2 = __hip_atomic_load(src + 2, __ATOMIC_RELAXED, __HIP_MEMORY_SCOPE_AGENT);
                d  = __hip_atomic_load(src + 3, __ATOMIC_RELAXED, __HIP_MEMORY_SCOPE_AGENT);
                if (((a >> 16) == tag) && ((b >> 16) == tag) &&
                    ((c2 >> 16) == tag) && ((d >> 16) == tag)) break;
                __builtin_amdgcn_s_sleep(1);
            }
            h0 = bf16_bits_to_f32(a & 0xFFFFu);
            h1 = bf16_bits_to_f32(b & 0xFFFFu);
            h2 = bf16_bits_to_f32(c2 & 0xFFFFu);
            h3 = bf16_bits_to_f32(d & 0xFFFFu);
        } else {
            h0 = h1 = h2 = h3 = 0.f;
        }

        // --- 16 partial dot products from registers ---
        float partial[16];
        #pragma unroll
        for (int r = 0; r < 16; ++r)
            partial[r] = Wreg[r][0] * h0 + Wreg[r][1] * h1
                       + Wreg[r][2] * h2 + Wreg[r][3] * h3;

        // --- in-wave butterfly reduction (all lanes end with full sums) ---
        #pragma unroll
        for (int r = 0; r < 16; ++r) {
            float v = partial[r];
            v += __shfl_xor(v, 1);  v += __shfl_xor(v, 2);
            v += __shfl_xor(v, 4);  v += __shfl_xor(v, 8);
            v += __shfl_xor(v, 16); v += __shfl_xor(v, 32);
            partial[r] = v;
        }
        // one lane per wave writes its 16 sums (static indexing)
        if (lane == 0) {
            #pragma unroll
            for (int r = 0; r < 16; ++r) ws_part[wv][r] = partial[r];
        }
        __syncthreads();

        // --- wave 0: combine waves, gates, cell update, publish ---
        // (waves 1-3 race ahead to step t+1; their poll blocks on our publish,
        //  so ws_part cannot be overwritten before wave 0 reads it)
        if (wv == 0) {
            float rowsum = 0.f;
            if (lane < 16)
                rowsum = ws_part[0][lane] + ws_part[1][lane]
                       + ws_part[2][lane] + ws_part[3][lane] + pre;
            const float gf = __shfl_down(rowsum, 4);
            const float gg = __shfl_down(rowsum, 8);
            const float go = __shfl_down(rowsum, 12);
            if (lane < 4) {
                const float ig = sigmoidf_(rowsum);
                const float fg = sigmoidf_(gf);
                const float g2 = tanhf(gg);
                const float og = sigmoidf_(go);
                c_reg = fg * c_reg + ig * g2;
                const float h = og * tanhf(c_reg);
                hs[(size_t)t * 1024 + w * 4 + lane] = h;
                const unsigned word = ((unsigned)t << 16) | f32_to_bf16_bits(h);
                __hip_atomic_store(&hbuf[(t & 1) * 1024 + w * 4 + lane], word,
                                   __ATOMIC_RELAXED, __HIP_MEMORY_SCOPE_AGENT);
            }
        }
    }
}

// ---------------------------------------------------------------------------
// Tag projection + log_softmax: one WG per sequence position.
// ---------------------------------------------------------------------------
__global__ __launch_bounds__(256) void tag_kernel(
    const float* __restrict__ hs, const float* __restrict__ Wtag,
    const float* __restrict__ btag, float* __restrict__ out)
{
    const int t = blockIdx.x;
    __shared__ float hrow[1024];
    __shared__ float logit[64];
    const int tid = threadIdx.x;
    for (int j = tid; j < 1024; j += 256) hrow[j] = hs[(size_t)t * 1024 + j];
    __syncthreads();
    const int j = tid >> 2, p = tid & 3;   // 4 lanes per tag
    float acc = 0.f;
    for (int k = p * 256; k < p * 256 + 256; ++k)
        acc += hrow[k] * Wtag[(size_t)j * 1024 + k];
    acc += __shfl_xor(acc, 1);
    acc += __shfl_xor(acc, 2);
    if (p == 0) logit[j] = acc + btag[j];
    __syncthreads();
    if (tid < 64) {
        float l = logit[tid];
        float m = l;
        #pragma unroll
        for (int off = 1; off < 64; off <<= 1) m = fmaxf(m, __shfl_xor(m, off));
        float e = expf(l - m);
        float ssum = e;
        #pragma unroll
        for (int off = 1; off < 64; off <<= 1) ssum += __shfl_xor(ssum, off);
        out[(size_t)t * 64 + tid] = l - m - logf(ssum);
    }
}

// ---------------------------------------------------------------------------
extern "C" void kernel_launch(void* const* d_in, const int* in_sizes, int n_in,
                              void* d_out, int out_size, void* d_ws, size_t ws_size,
                              hipStream_t stream)
{
    const int*   char_idx = (const int*)  d_in[0];
    const int*   word_idx = (const int*)  d_in[1];
    const float* Wemb     = (const float*)d_in[2];
    const float* Wec      = (const float*)d_in[3];
    const float* Wihc     = (const float*)d_in[4];
    const float* Whhc     = (const float*)d_in[5];
    const float* bihc     = (const float*)d_in[6];
    const float* bhhc     = (const float*)d_in[7];
    const float* Wih      = (const float*)d_in[8];
    const float* Whh      = (const float*)d_in[9];
    const float* bih      = (const float*)d_in[10];
    const float* bhh      = (const float*)d_in[11];
    const float* Wtag     = (const float*)d_in[12];
    const float* btag     = (const float*)d_in[13];
    float* out = (float*)d_out;

    // Workspace layout (fp32 elements). Total ~104 MB.
    float* ws      = (float*)d_ws;
    float* h_c     = ws;                               // 4096*256
    float* c_c     = h_c    + (size_t)SLEN * HCD;      // 4096*256
    float* gatesc  = c_c    + (size_t)SLEN * HCD;      // 4096*1024
    float* precomp = gatesc + (size_t)SLEN * 1024;     // 4096*4096
    float* hs      = precomp + (size_t)SLEN * 4096;    // 4096*1024
    unsigned int* hbuf = (unsigned int*)(hs + (size_t)SLEN * HD);  // 2*1024 u32

    hipMemsetAsync(h_c,  0, (size_t)SLEN * HCD * sizeof(float), stream);
    hipMemsetAsync(c_c,  0, (size_t)SLEN * HCD * sizeof(float), stream);
    // 0xFF -> tag 0xFFFF, which never matches any step tag in [0, 4094]
    hipMemsetAsync(hbuf, 0xFF, 2048 * sizeof(unsigned int), stream);

    // Char-level LSTM: 12 sequential steps, batched over all 4096 words
    for (int t = 0; t < CLEN; ++t) {
        char_gemm<<<dim3(SLEN / 64, 1024 / 64), 256, 0, stream>>>(
            char_idx, t, Wec, Wihc, Whhc, bihc, bhhc, h_c, gatesc);
        char_cell<<<(SLEN * HCD) / 256, 256, 0, stream>>>(gatesc, h_c, c_c);
    }

    // Word-level input projection for all timesteps (h_c now holds h_char)
    word_gemm<<<dim3(SLEN / 64, 4096 / 64), 256, 0, stream>>>(
        word_idx, Wemb, h_c, Wih, bih, bhh, precomp);

    // Sequential word-level LSTM recurrence (persistent, fence-free handoff)
    word_rec<<<256, 256, 0, stream>>>(precomp, Whh, hs, hbuf);

    // Tag projection + log_softmax
    tag_kernel<<<SLEN, 256, 0, stream>>>(hs, Wtag, btag, out);
}

// Round 4
// 3900.284 us; speedup vs baseline: 25.9823x; 5.1264x over previous
//
#include <hip/hip_runtime.h>
#include <hip/hip_bf16.h>

// Dims (fixed by the reference)
#define SLEN 4096
#define CLEN 12
#define ECD  256
#define HCD  256
#define ED   1024
#define HD   1024
#define TD   64
#define NSLOT 32          // WGs per XCD group (32 units each)
#define POLL_LIMIT 8192   // bailout for underfilled groups; healthy wait ~10

typedef __fp16 h2_t __attribute__((ext_vector_type(2)));
typedef unsigned  uv4 __attribute__((ext_vector_type(4)));

__device__ __forceinline__ float sigmoidf_(float x) { return 1.f / (1.f + __expf(-x)); }
__device__ __forceinline__ float tanh_fast(float x) {
    float ax = fabsf(x);
    float e = __expf(2.f * ax);          // inf-safe: e=inf -> t=1
    float t = 1.f - 2.f / (e + 1.f);
    return copysignf(t, x);
}
__device__ __forceinline__ h2_t bc_h2(unsigned u) { return __builtin_bit_cast(h2_t, u); }

// ---------------------------------------------------------------------------
// Char-level LSTM step GEMM: M=4096, N=1024, K=512.
// ---------------------------------------------------------------------------
__global__ __launch_bounds__(256) void char_gemm(
    const int* __restrict__ char_idx, int t,
    const float* __restrict__ Wec,
    const float* __restrict__ Wihc, const float* __restrict__ Whhc,
    const float* __restrict__ bihc, const float* __restrict__ bhhc,
    const float* __restrict__ h_c, float* __restrict__ gates)
{
    __shared__ float As[16][65];
    __shared__ float Bs[16][65];
    __shared__ int   cidx[64];
    const int tid = threadIdx.x;
    const int m0 = blockIdx.x * 64;
    const int n0 = blockIdx.y * 64;
    if (tid < 64) cidx[tid] = char_idx[(m0 + tid) * CLEN + t];
    __syncthreads();

    float acc[4][4] = {};
    const int tm = tid >> 4, tn = tid & 15;

    for (int k0 = 0; k0 < 512; k0 += 16) {
        #pragma unroll
        for (int i = 0; i < 4; ++i) {
            int e = tid + i * 256;
            int k = e >> 6, m = e & 63;
            int kk = k0 + k;
            float v;
            if (kk < 256) v = Wec[cidx[m] * 256 + kk];
            else          v = h_c[(size_t)(m0 + m) * 256 + (kk - 256)];
            As[k][m] = v;
        }
        #pragma unroll
        for (int i = 0; i < 4; ++i) {
            int e = tid + i * 256;
            int k = e >> 6, n = e & 63;
            int kk = k0 + k;
            int r = n0 + n;
            float v;
            if (kk < 256) v = Wihc[r * 256 + kk];
            else          v = Whhc[r * 256 + (kk - 256)];
            Bs[k][n] = v;
        }
        __syncthreads();
        #pragma unroll
        for (int k = 0; k < 16; ++k) {
            float a[4], b[4];
            #pragma unroll
            for (int i = 0; i < 4; ++i) a[i] = As[k][tm * 4 + i];
            #pragma unroll
            for (int j = 0; j < 4; ++j) b[j] = Bs[k][tn * 4 + j];
            #pragma unroll
            for (int i = 0; i < 4; ++i)
                #pragma unroll
                for (int j = 0; j < 4; ++j) acc[i][j] += a[i] * b[j];
        }
        __syncthreads();
    }
    #pragma unroll
    for (int i = 0; i < 4; ++i) {
        int m = m0 + tm * 4 + i;
        #pragma unroll
        for (int j = 0; j < 4; ++j) {
            int r = n0 + tn * 4 + j;
            gates[(size_t)m * 1024 + r] = acc[i][j] + bihc[r] + bhhc[r];
        }
    }
}

__global__ __launch_bounds__(256) void char_cell(
    const float* __restrict__ gates, float* __restrict__ h, float* __restrict__ c)
{
    int idx = blockIdx.x * 256 + threadIdx.x;      // 4096*256
    int s = idx >> 8, u = idx & 255;
    const float* g = gates + (size_t)s * 1024;
    float ig = sigmoidf_(g[u]);
    float fg = sigmoidf_(g[256 + u]);
    float gg = tanh_fast(g[512 + u]);
    float og = sigmoidf_(g[768 + u]);
    float cn = fg * c[idx] + ig * gg;
    c[idx] = cn;
    h[idx] = og * tanh_fast(cn);
}

// ---------------------------------------------------------------------------
// Word-level input precompute GEMM: M=4096, N=4096, K=1280.
// ---------------------------------------------------------------------------
__global__ __launch_bounds__(256) void word_gemm(
    const int* __restrict__ word_idx,
    const float* __restrict__ Wemb,
    const float* __restrict__ h_char,
    const float* __restrict__ Wih,
    const float* __restrict__ bih, const float* __restrict__ bhh,
    float* __restrict__ precomp)
{
    __shared__ float As[16][65];
    __shared__ float Bs[16][65];
    __shared__ int   widx[64];
    const int tid = threadIdx.x;
    const int m0 = blockIdx.x * 64;
    const int n0 = blockIdx.y * 64;
    if (tid < 64) widx[tid] = word_idx[m0 + tid];
    __syncthreads();

    float acc[4][4] = {};
    const int tm = tid >> 4, tn = tid & 15;

    for (int k0 = 0; k0 < 1280; k0 += 16) {
        #pragma unroll
        for (int i = 0; i < 4; ++i) {
            int e = tid + i * 256;
            int k = e >> 6, m = e & 63;
            int kk = k0 + k;
            float v;
            if (kk < 1024) v = Wemb[(size_t)widx[m] * 1024 + kk];
            else           v = h_char[(size_t)(m0 + m) * 256 + (kk - 1024)];
            As[k][m] = v;
        }
        #pragma unroll
        for (int i = 0; i < 4; ++i) {
            int e = tid + i * 256;
            int k = e >> 6, n = e & 63;
            Bs[k][n] = Wih[(size_t)(n0 + n) * 1280 + (k0 + k)];
        }
        __syncthreads();
        #pragma unroll
        for (int k = 0; k < 16; ++k) {
            float a[4], b[4];
            #pragma unroll
            for (int i = 0; i < 4; ++i) a[i] = As[k][tm * 4 + i];
            #pragma unroll
            for (int j = 0; j < 4; ++j) b[j] = Bs[k][tn * 4 + j];
            #pragma unroll
            for (int i = 0; i < 4; ++i)
                #pragma unroll
                for (int j = 0; j < 4; ++j) acc[i][j] += a[i] * b[j];
        }
        __syncthreads();
    }
    #pragma unroll
    for (int i = 0; i < 4; ++i) {
        int m = m0 + tm * 4 + i;
        #pragma unroll
        for (int j = 0; j < 4; ++j) {
            int r = n0 + tn * 4 + j;
            precomp[(size_t)m * 4096 + r] = acc[i][j] + bih[r] + bhh[r];
        }
    }
}

// ---------------------------------------------------------------------------
// Word-level LSTM recurrence v3: per-XCD redundant groups, L2-local handoff.
//
// 256 WGs x 256 thr; ~300+ VGPR -> 1 WG/CU -> all resident -> 32/XCD.
// Each XCD group computes the FULL recurrence independently (bitwise identical
// across groups); zero cross-XCD traffic. WG (slot s) owns units [32s,32s+32),
// wave v owns units base_u=32s+8v..+8. Lane m=lane&31 covers h-cols
// [32m,32m+32); half q=lane>>5 computes gates {2q,2q+1} x 8 units.
// W_hh slice in registers as fp16x2 (256 VGPR-words). Handoff: packed-fp16 h
// + per-wave tagged summary, all sc0 (served by XCD-local L2). Producer
// orders data->summary with s_waitcnt vmcnt(0). Double-buffered by parity.
// Poll timeout guarantees termination; pigeonhole guarantees >=1 full group.
// ---------------------------------------------------------------------------
__global__ __launch_bounds__(256, 1) void word_rec(
    const float* __restrict__ precomp, const float* __restrict__ W_hh,
    float* __restrict__ hs, unsigned* hdata, unsigned* hsum, int* xcd_ctr)
{
    const int tid  = threadIdx.x;
    const int v    = tid >> 6;        // wave 0..3
    const int lane = tid & 63;
    const int q    = lane >> 5;       // gate-pair group 0..1
    const int m    = lane & 31;       // col-slice index
    const int j    = lane & 7;        // unit within wave

    __shared__ int s_vals[2];
    if (tid == 0) {
        unsigned xcc;
        asm volatile("s_getreg_b32 %0, hwreg(HW_REG_XCC_ID)" : "=s"(xcc));
        xcc &= 7u;
        s_vals[0] = (int)xcc;
        s_vals[1] = atomicAdd(&xcd_ctr[xcc], 1);
    }
    __syncthreads();
    const int xcc  = s_vals[0];
    const int slot = s_vals[1];
    if (slot >= NSLOT) return;        // surplus WG (shouldn't happen at grid=256)

    const int base_u = slot * 32 + v * 8;
    unsigned* hdata_x = hdata + xcc * 1024;   // 2 parities x 512 words
    unsigned* hsum_x  = hsum  + xcc * 256;    // 2 parities x 128 words

    // --- W_hh slice -> registers as fp16 pairs: 16 rows x 32 cols ---
    // row r: gate g = 2q + (r>>3), unit = r&7 ; cols [32m, 32m+32)
    h2_t wp[16][16];
    #pragma unroll
    for (int r = 0; r < 16; ++r) {
        const int grow = (2 * q + (r >> 3)) * 1024 + base_u + (r & 7);
        const float4* rp = reinterpret_cast<const float4*>(
            W_hh + (size_t)grow * 1024 + 32 * m);
        #pragma unroll
        for (int d = 0; d < 8; ++d) {
            float4 f = rp[d];
            wp[r][2 * d]     = __builtin_amdgcn_cvt_pkrtz(f.x, f.y);
            wp[r][2 * d + 1] = __builtin_amdgcn_cvt_pkrtz(f.z, f.w);
        }
    }

    float c_reg = 0.f;

    for (int t = 0; t < SLEN; ++t) {
        const int pp = (t + 1) & 1;   // parity holding h_{t-1}
        const int pc = t & 1;         // parity we publish h_t into

        // prefetch precomp gate biases (L3-resident; overlaps the poll wait)
        float pre0 = 0.f, pre1 = 0.f, pre2 = 0.f, pre3 = 0.f;
        if (lane < 8) {
            const float* pr = precomp + (size_t)t * 4096 + base_u + j;
            pre0 = pr[0]; pre1 = pr[1024]; pre2 = pr[2048]; pre3 = pr[3072];
        }

        // --- acquire h_{t-1}: poll 4 summary words for slot m, then bulk load ---
        h2_t hp[16];
        if (t > 0) {
            const unsigned tgt = (unsigned)(t - 1);
            const unsigned* sp = hsum_x + pp * 128 + 4 * m;
            uv4 sv;
            int it = 0; bool dead = false;
            for (;;) {
                asm volatile("global_load_dwordx4 %0, %1, off sc0\n\t"
                             "s_waitcnt vmcnt(0)"
                             : "=&v"(sv) : "v"(sp) : "memory");
                bool ok = ((sv.x >> 16) == tgt) & ((sv.y >> 16) == tgt) &
                          ((sv.z >> 16) == tgt) & ((sv.w >> 16) == tgt);
                if (__all(ok)) break;
                if (++it > POLL_LIMIT) { dead = true; break; }
            }
            if (dead) return;          // underfilled group: exit, others cover hs

            const unsigned* dp = hdata_x + pp * 512 + 16 * m;
            uv4 d0, d1, d2, d3;
            asm volatile(
                "global_load_dwordx4 %0, %4, off sc0\n\t"
                "global_load_dwordx4 %1, %4, off offset:16 sc0\n\t"
                "global_load_dwordx4 %2, %4, off offset:32 sc0\n\t"
                "global_load_dwordx4 %3, %4, off offset:48 sc0\n\t"
                "s_waitcnt vmcnt(0)"
                : "=&v"(d0), "=&v"(d1), "=&v"(d2), "=&v"(d3)
                : "v"(dp) : "memory");
            hp[0]=bc_h2(d0.x);  hp[1]=bc_h2(d0.y);  hp[2]=bc_h2(d0.z);  hp[3]=bc_h2(d0.w);
            hp[4]=bc_h2(d1.x);  hp[5]=bc_h2(d1.y);  hp[6]=bc_h2(d1.z);  hp[7]=bc_h2(d1.w);
            hp[8]=bc_h2(d2.x);  hp[9]=bc_h2(d2.y);  hp[10]=bc_h2(d2.z); hp[11]=bc_h2(d2.w);
            hp[12]=bc_h2(d3.x); hp[13]=bc_h2(d3.y); hp[14]=bc_h2(d3.z); hp[15]=bc_h2(d3.w);
        } else {
            #pragma unroll
            for (int i = 0; i < 16; ++i) hp[i] = (h2_t)(__fp16)0;
        }

        // --- 16 rows: dot2 (4 indep accum chains) + 32-lane butterfly ---
        float sel = 0.f;
        #pragma unroll
        for (int r = 0; r < 16; ++r) {
            float a0 = 0.f, a1 = 0.f, a2 = 0.f, a3 = 0.f;
            #pragma unroll
            for (int d = 0; d < 4; ++d) {
                a0 = __builtin_amdgcn_fdot2(wp[r][d],      hp[d],      a0, false);
                a1 = __builtin_amdgcn_fdot2(wp[r][4 + d],  hp[4 + d],  a1, false);
                a2 = __builtin_amdgcn_fdot2(wp[r][8 + d],  hp[8 + d],  a2, false);
                a3 = __builtin_amdgcn_fdot2(wp[r][12 + d], hp[12 + d], a3, false);
            }
            float s = (a0 + a1) + (a2 + a3);
            s += __shfl_xor(s, 1);  s += __shfl_xor(s, 2);
            s += __shfl_xor(s, 4);  s += __shfl_xor(s, 8);
            s += __shfl_xor(s, 16);
            sel = ((lane & 31) == r) ? s : sel;
        }

        // gather 4 gates of unit j to lanes 0..7
        const float gi = __shfl(sel, j);
        const float gf = __shfl(sel, 8 + j);
        const float gg = __shfl(sel, 32 + j);
        const float go = __shfl(sel, 40 + j);

        float h = 0.f;
        if (lane < 8) {
            const float i_ = sigmoidf_(gi + pre0);
            const float f_ = sigmoidf_(gf + pre1);
            const float g_ = tanh_fast(gg + pre2);
            const float o_ = sigmoidf_(go + pre3);
            c_reg = f_ * c_reg + i_ * g_;
            h = o_ * tanh_fast(c_reg);
            hs[(size_t)t * 1024 + base_u + j] = h;   // identical across groups
        }

        // publish: packed fp16 pairs (lanes 0,2,4,6), then tagged summary
        const float hn = __shfl_down(h, 1);
        if (lane < 8 && (lane & 1) == 0) {
            unsigned pk = __builtin_bit_cast(unsigned,
                              __builtin_amdgcn_cvt_pkrtz(h, hn));
            unsigned* dpw = hdata_x + pc * 512 + slot * 16 + v * 4 + (lane >> 1);
            asm volatile("global_store_dword %0, %1, off sc0"
                         :: "v"(dpw), "v"(pk) : "memory");
        }
        if (lane == 0) {
            unsigned tw = ((unsigned)t << 16) | (unsigned)slot;
            unsigned* spw = hsum_x + pc * 128 + slot * 4 + v;
            asm volatile("s_waitcnt vmcnt(0)\n\t"
                         "global_store_dword %0, %1, off sc0"
                         :: "v"(spw), "v"(tw) : "memory");
        }
    }
}

// ---------------------------------------------------------------------------
// Tag projection + log_softmax (unchanged).
// ---------------------------------------------------------------------------
__global__ __launch_bounds__(256) void tag_kernel(
    const float* __restrict__ hs, const float* __restrict__ Wtag,
    const float* __restrict__ btag, float* __restrict__ out)
{
    const int t = blockIdx.x;
    __shared__ float hrow[1024];
    __shared__ float logit[64];
    const int tid = threadIdx.x;
    for (int j = tid; j < 1024; j += 256) hrow[j] = hs[(size_t)t * 1024 + j];
    __syncthreads();
    const int j = tid >> 2, p = tid & 3;   // 4 lanes per tag
    float acc = 0.f;
    for (int k = p * 256; k < p * 256 + 256; ++k)
        acc += hrow[k] * Wtag[(size_t)j * 1024 + k];
    acc += __shfl_xor(acc, 1);
    acc += __shfl_xor(acc, 2);
    if (p == 0) logit[j] = acc + btag[j];
    __syncthreads();
    if (tid < 64) {
        float l = logit[tid];
        float mx = l;
        #pragma unroll
        for (int off = 1; off < 64; off <<= 1) mx = fmaxf(mx, __shfl_xor(mx, off));
        float e = expf(l - mx);
        float ssum = e;
        #pragma unroll
        for (int off = 1; off < 64; off <<= 1) ssum += __shfl_xor(ssum, off);
        out[(size_t)t * 64 + tid] = l - mx - logf(ssum);
    }
}

// ---------------------------------------------------------------------------
extern "C" void kernel_launch(void* const* d_in, const int* in_sizes, int n_in,
                              void* d_out, int out_size, void* d_ws, size_t ws_size,
                              hipStream_t stream)
{
    const int*   char_idx = (const int*)  d_in[0];
    const int*   word_idx = (const int*)  d_in[1];
    const float* Wemb     = (const float*)d_in[2];
    const float* Wec      = (const float*)d_in[3];
    const float* Wihc     = (const float*)d_in[4];
    const float* Whhc     = (const float*)d_in[5];
    const float* bihc     = (const float*)d_in[6];
    const float* bhhc     = (const float*)d_in[7];
    const float* Wih      = (const float*)d_in[8];
    const float* Whh      = (const float*)d_in[9];
    const float* bih      = (const float*)d_in[10];
    const float* bhh      = (const float*)d_in[11];
    const float* Wtag     = (const float*)d_in[12];
    const float* btag     = (const float*)d_in[13];
    float* out = (float*)d_out;

    // Workspace layout (fp32 elements). Total ~104 MB + 40 KB.
    float* ws      = (float*)d_ws;
    float* h_c     = ws;                               // 4096*256
    float* c_c     = h_c    + (size_t)SLEN * HCD;      // 4096*256
    float* gatesc  = c_c    + (size_t)SLEN * HCD;      // 4096*1024
    float* precomp = gatesc + (size_t)SLEN * 1024;     // 4096*4096
    float* hs      = precomp + (size_t)SLEN * 4096;    // 4096*1024
    unsigned* hdata = (unsigned*)(hs + (size_t)SLEN * HD);  // 8 XCD * 2 * 512
    unsigned* hsum  = hdata + 8 * 1024;                     // 8 XCD * 2 * 128
    int* xcd_ctr    = (int*)(hsum + 8 * 256);               // 8

    (void)hipMemsetAsync(h_c,  0, (size_t)SLEN * HCD * sizeof(float), stream);
    (void)hipMemsetAsync(c_c,  0, (size_t)SLEN * HCD * sizeof(float), stream);
    // 0xFF -> summary tag 0xFFFF, never matches any step tag in [0, 4095]
    (void)hipMemsetAsync(hsum, 0xFF, 8 * 256 * sizeof(unsigned), stream);
    (void)hipMemsetAsync(xcd_ctr, 0, 8 * sizeof(int), stream);

    // Char-level LSTM: 12 sequential steps, batched over all 4096 words
    for (int t = 0; t < CLEN; ++t) {
        char_gemm<<<dim3(SLEN / 64, 1024 / 64), 256, 0, stream>>>(
            char_idx, t, Wec, Wihc, Whhc, bihc, bhhc, h_c, gatesc);
        char_cell<<<(SLEN * HCD) / 256, 256, 0, stream>>>(gatesc, h_c, c_c);
    }

    // Word-level input projection for all timesteps (h_c now holds h_char)
    word_gemm<<<dim3(SLEN / 64, 4096 / 64), 256, 0, stream>>>(
        word_idx, Wemb, h_c, Wih, bih, bhh, precomp);

    // Sequential word-level LSTM recurrence (per-XCD redundant, L2-local)
    word_rec<<<256, 256, 0, stream>>>(precomp, Whh, hs, hdata, hsum, xcd_ctr);

    // Tag projection + log_softmax
    tag_kernel<<<SLEN, 256, 0, stream>>>(hs, Wtag, btag, out);
}

// Round 5
// 1754.338 us; speedup vs baseline: 57.7645x; 2.2232x over previous
//
#include <hip/hip_runtime.h>
#include <hip/hip_bf16.h>

// Dims (fixed by the reference)
#define SLEN 4096
#define CLEN 12
#define ECD  256
#define HCD  256
#define ED   1024
#define HD   1024
#define TD   64
#define NSLOT 32          // WGs per XCD group (32 units each)
#define POLL_LIMIT 8192   // bailout for underfilled groups; healthy wait ~10
#define NC_PAD 16384      // Wec_b slot: 26*256*2=13312 B padded to 16 KB

typedef __fp16 h2_t __attribute__((ext_vector_type(2)));
typedef unsigned  uv4 __attribute__((ext_vector_type(4)));
typedef __attribute__((ext_vector_type(8))) short bf16x8;   // MFMA A/B frag (4 VGPR)
typedef __attribute__((ext_vector_type(4))) float f32x4;    // MFMA C/D frag

__device__ __forceinline__ float sigmoidf_(float x) { return 1.f / (1.f + __expf(-x)); }
__device__ __forceinline__ float tanh_fast(float x) {
    float ax = fabsf(x);
    float e = __expf(2.f * ax);          // inf-safe: e=inf -> t=1
    float t = 1.f - 2.f / (e + 1.f);
    return copysignf(t, x);
}
__device__ __forceinline__ h2_t bc_h2(unsigned u) { return __builtin_bit_cast(h2_t, u); }

// round-to-nearest-even f32 -> bf16 bits
__device__ __forceinline__ unsigned short bf16r(float f) {
    unsigned u = __float_as_uint(f);
    return (unsigned short)((u + 0x7FFFu + ((u >> 16) & 1u)) >> 16);
}

// ===========================================================================
// bf16 conversion / gather helpers (run once per call; memory-bound, tiny)
// ===========================================================================
__global__ __launch_bounds__(256) void conv_bf16(
    const float* __restrict__ src, unsigned short* __restrict__ dst, int n8)
{
    int i = blockIdx.x * 256 + threadIdx.x;
    if (i >= n8) return;
    const float4* s = reinterpret_cast<const float4*>(src + (size_t)i * 8);
    float4 a = s[0], b = s[1];
    unsigned short o[8] = { bf16r(a.x), bf16r(a.y), bf16r(a.z), bf16r(a.w),
                            bf16r(b.x), bf16r(b.y), bf16r(b.z), bf16r(b.w) };
    *reinterpret_cast<uint4*>(dst + (size_t)i * 8) = *reinterpret_cast<uint4*>(o);
}

// Bc[r][k] (bf16, [1024][512]) = k<256 ? W_ih_c[r][k] : W_hh_c[r][k-256]
__global__ __launch_bounds__(256) void build_Bc(
    const float* __restrict__ Wihc, const float* __restrict__ Whhc,
    unsigned short* __restrict__ Bc)
{
    int id = blockIdx.x * 256 + threadIdx.x;      // 1024*64
    int r = id >> 6, kc = id & 63;
    int k = kc * 8;
    const float* s = (k < 256) ? (Wihc + (size_t)r * 256 + k)
                               : (Whhc + (size_t)r * 256 + (k - 256));
    const float4* sv = reinterpret_cast<const float4*>(s);
    float4 a = sv[0], b = sv[1];
    unsigned short o[8] = { bf16r(a.x), bf16r(a.y), bf16r(a.z), bf16r(a.w),
                            bf16r(b.x), bf16r(b.y), bf16r(b.z), bf16r(b.w) };
    *reinterpret_cast<uint4*>(Bc + (size_t)id * 8) = *reinterpret_cast<uint4*>(o);
}

// Xw[s][k] (bf16, [4096][1280]) = k<1024 ? W_emb_word[word_idx[s]][k] : h_cb[s][k-1024]
__global__ __launch_bounds__(256) void build_Xw(
    const int* __restrict__ word_idx, const float* __restrict__ Wemb,
    const unsigned short* __restrict__ h_cb, unsigned short* __restrict__ Xw)
{
    int id = blockIdx.x * 256 + threadIdx.x;      // 4096*160
    int row = id / 160, c8 = id % 160;
    int k = c8 * 8;
    uint4 outv;
    if (k < 1024) {
        const float4* sv = reinterpret_cast<const float4*>(
            Wemb + (size_t)word_idx[row] * 1024 + k);
        float4 a = sv[0], b = sv[1];
        unsigned short o[8] = { bf16r(a.x), bf16r(a.y), bf16r(a.z), bf16r(a.w),
                                bf16r(b.x), bf16r(b.y), bf16r(b.z), bf16r(b.w) };
        outv = *reinterpret_cast<uint4*>(o);
    } else {
        outv = *reinterpret_cast<const uint4*>(h_cb + (size_t)row * 256 + (k - 1024));
    }
    *reinterpret_cast<uint4*>(Xw + (size_t)row * 1280 + k) = outv;
}

// ===========================================================================
// MFMA GEMM: C[M][N] = A[M][K](bf16) @ B[N][K](bf16)^T + bias0[n] + bias1[n]
// 128x128 tile, 256 thr (2x2 waves of 64x64), BK=64, reg-staged LDS with
// chunk-XOR swizzle (chunk16 ^= row&7) killing the 128B-stride read conflict.
// ===========================================================================
__global__ __launch_bounds__(256) void gemm_bf16_bt(
    const unsigned short* __restrict__ A, const unsigned short* __restrict__ B,
    const float* __restrict__ bias0, const float* __restrict__ bias1,
    float* __restrict__ C, int M, int N, int K)
{
    __shared__ unsigned short As[128 * 64];
    __shared__ unsigned short Bs[128 * 64];
    const int tid  = threadIdx.x;
    const int lane = tid & 63;
    const int wm = (tid >> 6) >> 1, wn = (tid >> 6) & 1;
    const int fr = lane & 15, fk = lane >> 4;
    const int n0 = blockIdx.x * 128;
    const int m0 = blockIdx.y * 128;

    uint4 ar[4], br[4];
    int rowi[4], kci[4];
    #pragma unroll
    for (int c = 0; c < 4; ++c) {
        int ch = c * 256 + tid;
        rowi[c] = ch >> 3; kci[c] = ch & 7;
    }

    auto load_tiles = [&](int k0) {
        #pragma unroll
        for (int c = 0; c < 4; ++c) {
            ar[c] = *reinterpret_cast<const uint4*>(
                A + (size_t)(m0 + rowi[c]) * K + k0 + kci[c] * 8);
            br[c] = *reinterpret_cast<const uint4*>(
                B + (size_t)(n0 + rowi[c]) * K + k0 + kci[c] * 8);
        }
    };

    f32x4 acc[4][4];
    #pragma unroll
    for (int i = 0; i < 4; ++i)
        #pragma unroll
        for (int j = 0; j < 4; ++j) acc[i][j] = f32x4{0.f, 0.f, 0.f, 0.f};

    load_tiles(0);
    for (int k0 = 0; k0 < K; k0 += 64) {
        __syncthreads();
        #pragma unroll
        for (int c = 0; c < 4; ++c) {
            int sw = kci[c] ^ (rowi[c] & 7);
            *reinterpret_cast<uint4*>(&As[rowi[c] * 64 + sw * 8]) = ar[c];
            *reinterpret_cast<uint4*>(&Bs[rowi[c] * 64 + sw * 8]) = br[c];
        }
        __syncthreads();
        if (k0 + 64 < K) load_tiles(k0 + 64);
        #pragma unroll
        for (int ks = 0; ks < 2; ++ks) {
            bf16x8 af[4], bfr[4];
            #pragma unroll
            for (int i = 0; i < 4; ++i) {
                int ra = wm * 64 + i * 16 + fr;
                af[i] = *reinterpret_cast<const bf16x8*>(
                    &As[ra * 64 + (((ks * 4 + fk) ^ (ra & 7)) << 3)]);
                int rb = wn * 64 + i * 16 + fr;
                bfr[i] = *reinterpret_cast<const bf16x8*>(
                    &Bs[rb * 64 + (((ks * 4 + fk) ^ (rb & 7)) << 3)]);
            }
            #pragma unroll
            for (int i = 0; i < 4; ++i)
                #pragma unroll
                for (int j = 0; j < 4; ++j)
                    acc[i][j] = __builtin_amdgcn_mfma_f32_16x16x32_bf16(
                        af[i], bfr[j], acc[i][j], 0, 0, 0);
        }
    }

    // epilogue: D row=(lane>>4)*4+reg, col=lane&15  [verified C/D layout]
    const int colb = n0 + wn * 64 + fr;
    float bsum[4];
    #pragma unroll
    for (int j = 0; j < 4; ++j) bsum[j] = bias0[colb + j * 16] + bias1[colb + j * 16];
    #pragma unroll
    for (int i = 0; i < 4; ++i) {
        int row0 = m0 + wm * 64 + i * 16 + fk * 4;
        #pragma unroll
        for (int j = 0; j < 4; ++j) {
            int col = colb + j * 16;
            #pragma unroll
            for (int r = 0; r < 4; ++r)
                C[(size_t)(row0 + r) * N + col] = acc[i][j][r] + bsum[j];
        }
    }
}

// ===========================================================================
// Char-step MFMA GEMM: A gathered on the fly from (Wec_b via char_idx | h_cb),
// B = Bc [1024][512], K=512 fixed. M=4096, N=1024.
// ===========================================================================
__global__ __launch_bounds__(256) void char_gemm_mfma(
    const int* __restrict__ char_idx, int t,
    const unsigned short* __restrict__ Wec_b,
    const unsigned short* __restrict__ h_cb,
    const unsigned short* __restrict__ Bc,
    const float* __restrict__ bias0, const float* __restrict__ bias1,
    float* __restrict__ C)
{
    const int K = 512, N = 1024;
    __shared__ unsigned short As[128 * 64];
    __shared__ unsigned short Bs[128 * 64];
    const int tid  = threadIdx.x;
    const int lane = tid & 63;
    const int wm = (tid >> 6) >> 1, wn = (tid >> 6) & 1;
    const int fr = lane & 15, fk = lane >> 4;
    const int n0 = blockIdx.x * 128;
    const int m0 = blockIdx.y * 128;

    uint4 ar[4], br[4];
    int rowi[4], kci[4], cidx[4];
    #pragma unroll
    for (int c = 0; c < 4; ++c) {
        int ch = c * 256 + tid;
        rowi[c] = ch >> 3; kci[c] = ch & 7;
        cidx[c] = char_idx[(m0 + rowi[c]) * CLEN + t];
    }

    auto load_tiles = [&](int k0) {
        #pragma unroll
        for (int c = 0; c < 4; ++c) {
            int ke = k0 + kci[c] * 8;
            const unsigned short* s = (ke < 256)
                ? (Wec_b + (size_t)cidx[c] * 256 + ke)
                : (h_cb + (size_t)(m0 + rowi[c]) * 256 + (ke - 256));
            ar[c] = *reinterpret_cast<const uint4*>(s);
            br[c] = *reinterpret_cast<const uint4*>(
                Bc + (size_t)(n0 + rowi[c]) * K + k0 + kci[c] * 8);
        }
    };

    f32x4 acc[4][4];
    #pragma unroll
    for (int i = 0; i < 4; ++i)
        #pragma unroll
        for (int j = 0; j < 4; ++j) acc[i][j] = f32x4{0.f, 0.f, 0.f, 0.f};

    load_tiles(0);
    for (int k0 = 0; k0 < K; k0 += 64) {
        __syncthreads();
        #pragma unroll
        for (int c = 0; c < 4; ++c) {
            int sw = kci[c] ^ (rowi[c] & 7);
            *reinterpret_cast<uint4*>(&As[rowi[c] * 64 + sw * 8]) = ar[c];
            *reinterpret_cast<uint4*>(&Bs[rowi[c] * 64 + sw * 8]) = br[c];
        }
        __syncthreads();
        if (k0 + 64 < K) load_tiles(k0 + 64);
        #pragma unroll
        for (int ks = 0; ks < 2; ++ks) {
            bf16x8 af[4], bfr[4];
            #pragma unroll
            for (int i = 0; i < 4; ++i) {
                int ra = wm * 64 + i * 16 + fr;
                af[i] = *reinterpret_cast<const bf16x8*>(
                    &As[ra * 64 + (((ks * 4 + fk) ^ (ra & 7)) << 3)]);
                int rb = wn * 64 + i * 16 + fr;
                bfr[i] = *reinterpret_cast<const bf16x8*>(
                    &Bs[rb * 64 + (((ks * 4 + fk) ^ (rb & 7)) << 3)]);
            }
            #pragma unroll
            for (int i = 0; i < 4; ++i)
                #pragma unroll
                for (int j = 0; j < 4; ++j)
                    acc[i][j] = __builtin_amdgcn_mfma_f32_16x16x32_bf16(
                        af[i], bfr[j], acc[i][j], 0, 0, 0);
        }
    }

    const int colb = n0 + wn * 64 + fr;
    float bsum[4];
    #pragma unroll
    for (int j = 0; j < 4; ++j) bsum[j] = bias0[colb + j * 16] + bias1[colb + j * 16];
    #pragma unroll
    for (int i = 0; i < 4; ++i) {
        int row0 = m0 + wm * 64 + i * 16 + fk * 4;
        #pragma unroll
        for (int j = 0; j < 4; ++j) {
            int col = colb + j * 16;
            #pragma unroll
            for (int r = 0; r < 4; ++r)
                C[(size_t)(row0 + r) * N + col] = acc[i][j][r] + bsum[j];
        }
    }
}

// Char LSTM cell update: gates f32 -> c f32, h bf16 (4 units/thread)
__global__ __launch_bounds__(256) void char_cell(
    const float* __restrict__ gates, float* __restrict__ c,
    unsigned short* __restrict__ h_cb)
{
    int i = blockIdx.x * 256 + threadIdx.x;     // 4096*64
    int s = i >> 6, u = (i & 63) * 4;
    const float* g = gates + (size_t)s * 1024;
    float4 gi = *reinterpret_cast<const float4*>(g + u);
    float4 gf = *reinterpret_cast<const float4*>(g + 256 + u);
    float4 gg = *reinterpret_cast<const float4*>(g + 512 + u);
    float4 go = *reinterpret_cast<const float4*>(g + 768 + u);
    float4 cc = *reinterpret_cast<float4*>(c + (size_t)s * 256 + u);
    float h[4];
    float cn;
    cn = sigmoidf_(gf.x) * cc.x + sigmoidf_(gi.x) * tanh_fast(gg.x);
    cc.x = cn; h[0] = sigmoidf_(go.x) * tanh_fast(cn);
    cn = sigmoidf_(gf.y) * cc.y + sigmoidf_(gi.y) * tanh_fast(gg.y);
    cc.y = cn; h[1] = sigmoidf_(go.y) * tanh_fast(cn);
    cn = sigmoidf_(gf.z) * cc.z + sigmoidf_(gi.z) * tanh_fast(gg.z);
    cc.z = cn; h[2] = sigmoidf_(go.z) * tanh_fast(cn);
    cn = sigmoidf_(gf.w) * cc.w + sigmoidf_(gi.w) * tanh_fast(gg.w);
    cc.w = cn; h[3] = sigmoidf_(go.w) * tanh_fast(cn);
    *reinterpret_cast<float4*>(c + (size_t)s * 256 + u) = cc;
    unsigned short o[4] = { bf16r(h[0]), bf16r(h[1]), bf16r(h[2]), bf16r(h[3]) };
    *reinterpret_cast<uint2*>(h_cb + (size_t)s * 256 + u) =
        *reinterpret_cast<uint2*>(o);
}

// ---------------------------------------------------------------------------
// Word-level LSTM recurrence (unchanged from R4): per-XCD redundant groups,
// L2-local sc0 handoff, register-resident fp16 W_hh.
// ---------------------------------------------------------------------------
__global__ __launch_bounds__(256, 1) void word_rec(
    const float* __restrict__ precomp, const float* __restrict__ W_hh,
    float* __restrict__ hs, unsigned* hdata, unsigned* hsum, int* xcd_ctr)
{
    const int tid  = threadIdx.x;
    const int v    = tid >> 6;        // wave 0..3
    const int lane = tid & 63;
    const int q    = lane >> 5;       // gate-pair group 0..1
    const int m    = lane & 31;       // col-slice index
    const int j    = lane & 7;        // unit within wave

    __shared__ int s_vals[2];
    if (tid == 0) {
        unsigned xcc;
        asm volatile("s_getreg_b32 %0, hwreg(HW_REG_XCC_ID)" : "=s"(xcc));
        xcc &= 7u;
        s_vals[0] = (int)xcc;
        s_vals[1] = atomicAdd(&xcd_ctr[xcc], 1);
    }
    __syncthreads();
    const int xcc  = s_vals[0];
    const int slot = s_vals[1];
    if (slot >= NSLOT) return;

    const int base_u = slot * 32 + v * 8;
    unsigned* hdata_x = hdata + xcc * 1024;
    unsigned* hsum_x  = hsum  + xcc * 256;

    h2_t wp[16][16];
    #pragma unroll
    for (int r = 0; r < 16; ++r) {
        const int grow = (2 * q + (r >> 3)) * 1024 + base_u + (r & 7);
        const float4* rp = reinterpret_cast<const float4*>(
            W_hh + (size_t)grow * 1024 + 32 * m);
        #pragma unroll
        for (int d = 0; d < 8; ++d) {
            float4 f = rp[d];
            wp[r][2 * d]     = __builtin_amdgcn_cvt_pkrtz(f.x, f.y);
            wp[r][2 * d + 1] = __builtin_amdgcn_cvt_pkrtz(f.z, f.w);
        }
    }

    float c_reg = 0.f;

    for (int t = 0; t < SLEN; ++t) {
        const int pp = (t + 1) & 1;
        const int pc = t & 1;

        float pre0 = 0.f, pre1 = 0.f, pre2 = 0.f, pre3 = 0.f;
        if (lane < 8) {
            const float* pr = precomp + (size_t)t * 4096 + base_u + j;
            pre0 = pr[0]; pre1 = pr[1024]; pre2 = pr[2048]; pre3 = pr[3072];
        }

        h2_t hp[16];
        if (t > 0) {
            const unsigned tgt = (unsigned)(t - 1);
            const unsigned* sp = hsum_x + pp * 128 + 4 * m;
            uv4 sv;
            int it = 0; bool dead = false;
            for (;;) {
                asm volatile("global_load_dwordx4 %0, %1, off sc0\n\t"
                             "s_waitcnt vmcnt(0)"
                             : "=&v"(sv) : "v"(sp) : "memory");
                bool ok = ((sv.x >> 16) == tgt) & ((sv.y >> 16) == tgt) &
                          ((sv.z >> 16) == tgt) & ((sv.w >> 16) == tgt);
                if (__all(ok)) break;
                if (++it > POLL_LIMIT) { dead = true; break; }
            }
            if (dead) return;

            const unsigned* dp = hdata_x + pp * 512 + 16 * m;
            uv4 d0, d1, d2, d3;
            asm volatile(
                "global_load_dwordx4 %0, %4, off sc0\n\t"
                "global_load_dwordx4 %1, %4, off offset:16 sc0\n\t"
                "global_load_dwordx4 %2, %4, off offset:32 sc0\n\t"
                "global_load_dwordx4 %3, %4, off offset:48 sc0\n\t"
                "s_waitcnt vmcnt(0)"
                : "=&v"(d0), "=&v"(d1), "=&v"(d2), "=&v"(d3)
                : "v"(dp) : "memory");
            hp[0]=bc_h2(d0.x);  hp[1]=bc_h2(d0.y);  hp[2]=bc_h2(d0.z);  hp[3]=bc_h2(d0.w);
            hp[4]=bc_h2(d1.x);  hp[5]=bc_h2(d1.y);  hp[6]=bc_h2(d1.z);  hp[7]=bc_h2(d1.w);
            hp[8]=bc_h2(d2.x);  hp[9]=bc_h2(d2.y);  hp[10]=bc_h2(d2.z); hp[11]=bc_h2(d2.w);
            hp[12]=bc_h2(d3.x); hp[13]=bc_h2(d3.y); hp[14]=bc_h2(d3.z); hp[15]=bc_h2(d3.w);
        } else {
            #pragma unroll
            for (int i = 0; i < 16; ++i) hp[i] = (h2_t)(__fp16)0;
        }

        float sel = 0.f;
        #pragma unroll
        for (int r = 0; r < 16; ++r) {
            float a0 = 0.f, a1 = 0.f, a2 = 0.f, a3 = 0.f;
            #pragma unroll
            for (int d = 0; d < 4; ++d) {
                a0 = __builtin_amdgcn_fdot2(wp[r][d],      hp[d],      a0, false);
                a1 = __builtin_amdgcn_fdot2(wp[r][4 + d],  hp[4 + d],  a1, false);
                a2 = __builtin_amdgcn_fdot2(wp[r][8 + d],  hp[8 + d],  a2, false);
                a3 = __builtin_amdgcn_fdot2(wp[r][12 + d], hp[12 + d], a3, false);
            }
            float s = (a0 + a1) + (a2 + a3);
            s += __shfl_xor(s, 1);  s += __shfl_xor(s, 2);
            s += __shfl_xor(s, 4);  s += __shfl_xor(s, 8);
            s += __shfl_xor(s, 16);
            sel = ((lane & 31) == r) ? s : sel;
        }

        const float gi = __shfl(sel, j);
        const float gf = __shfl(sel, 8 + j);
        const float gg = __shfl(sel, 32 + j);
        const float go = __shfl(sel, 40 + j);

        float h = 0.f;
        if (lane < 8) {
            const float i_ = sigmoidf_(gi + pre0);
            const float f_ = sigmoidf_(gf + pre1);
            const float g_ = tanh_fast(gg + pre2);
            const float o_ = sigmoidf_(go + pre3);
            c_reg = f_ * c_reg + i_ * g_;
            h = o_ * tanh_fast(c_reg);
            hs[(size_t)t * 1024 + base_u + j] = h;
        }

        const float hn = __shfl_down(h, 1);
        if (lane < 8 && (lane & 1) == 0) {
            unsigned pk = __builtin_bit_cast(unsigned,
                              __builtin_amdgcn_cvt_pkrtz(h, hn));
            unsigned* dpw = hdata_x + pc * 512 + slot * 16 + v * 4 + (lane >> 1);
            asm volatile("global_store_dword %0, %1, off sc0"
                         :: "v"(dpw), "v"(pk) : "memory");
        }
        if (lane == 0) {
            unsigned tw = ((unsigned)t << 16) | (unsigned)slot;
            unsigned* spw = hsum_x + pc * 128 + slot * 4 + v;
            asm volatile("s_waitcnt vmcnt(0)\n\t"
                         "global_store_dword %0, %1, off sc0"
                         :: "v"(spw), "v"(tw) : "memory");
        }
    }
}

// ---------------------------------------------------------------------------
// Tag projection + log_softmax (unchanged).
// ---------------------------------------------------------------------------
__global__ __launch_bounds__(256) void tag_kernel(
    const float* __restrict__ hs, const float* __restrict__ Wtag,
    const float* __restrict__ btag, float* __restrict__ out)
{
    const int t = blockIdx.x;
    __shared__ float hrow[1024];
    __shared__ float logit[64];
    const int tid = threadIdx.x;
    for (int j = tid; j < 1024; j += 256) hrow[j] = hs[(size_t)t * 1024 + j];
    __syncthreads();
    const int j = tid >> 2, p = tid & 3;
    float acc = 0.f;
    for (int k = p * 256; k < p * 256 + 256; ++k)
        acc += hrow[k] * Wtag[(size_t)j * 1024 + k];
    acc += __shfl_xor(acc, 1);
    acc += __shfl_xor(acc, 2);
    if (p == 0) logit[j] = acc + btag[j];
    __syncthreads();
    if (tid < 64) {
        float l = logit[tid];
        float mx = l;
        #pragma unroll
        for (int off = 1; off < 64; off <<= 1) mx = fmaxf(mx, __shfl_xor(mx, off));
        float e = expf(l - mx);
        float ssum = e;
        #pragma unroll
        for (int off = 1; off < 64; off <<= 1) ssum += __shfl_xor(ssum, off);
        out[(size_t)t * 64 + tid] = l - mx - logf(ssum);
    }
}

// ---------------------------------------------------------------------------
extern "C" void kernel_launch(void* const* d_in, const int* in_sizes, int n_in,
                              void* d_out, int out_size, void* d_ws, size_t ws_size,
                              hipStream_t stream)
{
    const int*   char_idx = (const int*)  d_in[0];
    const int*   word_idx = (const int*)  d_in[1];
    const float* Wemb     = (const float*)d_in[2];
    const float* Wec      = (const float*)d_in[3];
    const float* Wihc     = (const float*)d_in[4];
    const float* Whhc     = (const float*)d_in[5];
    const float* bihc     = (const float*)d_in[6];
    const float* bhhc     = (const float*)d_in[7];
    const float* Wih      = (const float*)d_in[8];
    const float* Whh      = (const float*)d_in[9];
    const float* bih      = (const float*)d_in[10];
    const float* bhh      = (const float*)d_in[11];
    const float* Wtag     = (const float*)d_in[12];
    const float* btag     = (const float*)d_in[13];
    float* out = (float*)d_out;

    // Workspace layout (~124 MB), all segments 16B-aligned
    char* w = (char*)d_ws;
    float*          precomp = (float*)w;            w += (size_t)SLEN * 4096 * 4;
    float*          hs      = (float*)w;            w += (size_t)SLEN * HD * 4;
    float*          gatesc  = (float*)w;            w += (size_t)SLEN * 1024 * 4;
    unsigned short* Wihb    = (unsigned short*)w;   w += (size_t)4096 * 1280 * 2;
    unsigned short* Xw      = (unsigned short*)w;   w += (size_t)4096 * 1280 * 2;
    float*          c_c     = (float*)w;            w += (size_t)SLEN * HCD * 4;
    unsigned short* h_cb    = (unsigned short*)w;   w += (size_t)SLEN * HCD * 2;
    unsigned short* Bc      = (unsigned short*)w;   w += (size_t)1024 * 512 * 2;
    unsigned short* Wec_b   = (unsigned short*)w;   w += NC_PAD;
    unsigned*       hdata   = (unsigned*)w;         w += 8 * 1024 * 4;
    unsigned*       hsum    = (unsigned*)w;         w += 8 * 256 * 4;
    int*            xcd_ctr = (int*)w;

    (void)hipMemsetAsync(c_c,  0, (size_t)SLEN * HCD * sizeof(float), stream);
    (void)hipMemsetAsync(h_cb, 0, (size_t)SLEN * HCD * sizeof(unsigned short), stream);
    (void)hipMemsetAsync(hsum, 0xFF, 8 * 256 * sizeof(unsigned), stream);
    (void)hipMemsetAsync(xcd_ctr, 0, 8 * sizeof(int), stream);

    // --- one-time conversions ---
    conv_bf16<<<4, 256, 0, stream>>>(Wec, Wec_b, 26 * 256 / 8);
    build_Bc<<<256, 256, 0, stream>>>(Wihc, Whhc, Bc);
    conv_bf16<<<2560, 256, 0, stream>>>(Wih, Wihb, 4096 * 1280 / 8);

    // --- char-level LSTM: 12 sequential MFMA steps ---
    for (int t = 0; t < CLEN; ++t) {
        char_gemm_mfma<<<dim3(1024 / 128, SLEN / 128), 256, 0, stream>>>(
            char_idx, t, Wec_b, h_cb, Bc, bihc, bhhc, gatesc);
        char_cell<<<SLEN * 64 / 256, 256, 0, stream>>>(gatesc, c_c, h_cb);
    }

    // --- word input projection: gather X then one MFMA GEMM ---
    build_Xw<<<SLEN * 160 / 256, 256, 0, stream>>>(word_idx, Wemb, h_cb, Xw);
    gemm_bf16_bt<<<dim3(4096 / 128, SLEN / 128), 256, 0, stream>>>(
        Xw, Wihb, bih, bhh, precomp, SLEN, 4096, 1280);

    // --- sequential word-level LSTM recurrence (per-XCD redundant) ---
    word_rec<<<256, 256, 0, stream>>>(precomp, Whh, hs, hdata, hsum, xcd_ctr);

    // --- tag projection + log_softmax ---
    tag_kernel<<<SLEN, 256, 0, stream>>>(hs, Wtag, btag, out);
}

// Round 6
// 1744.248 us; speedup vs baseline: 58.0986x; 1.0058x over previous
//
#include <hip/hip_runtime.h>
#include <hip/hip_bf16.h>

// Dims (fixed by the reference)
#define SLEN 4096
#define CLEN 12
#define ECD  256
#define HCD  256
#define ED   1024
#define HD   1024
#define TD   64
#define NSLOT 32          // WGs per XCD group (32 units each)
#define POLL_LIMIT 8192   // bailout for underfilled groups

typedef __fp16 h2_t __attribute__((ext_vector_type(2)));
typedef unsigned  uv4 __attribute__((ext_vector_type(4)));
typedef __attribute__((ext_vector_type(8))) short bf16x8;   // MFMA A/B frag
typedef __attribute__((ext_vector_type(4))) float f32x4;    // MFMA C/D frag

__device__ __forceinline__ float sigmoidf_(float x) { return 1.f / (1.f + __expf(-x)); }
__device__ __forceinline__ float tanh_fast(float x) {
    float ax = fabsf(x);
    float e = __expf(2.f * ax);          // inf-safe
    float t = 1.f - 2.f / (e + 1.f);
    return copysignf(t, x);
}
__device__ __forceinline__ h2_t bc_h2(unsigned u) { return __builtin_bit_cast(h2_t, u); }
__device__ __forceinline__ unsigned short bf16r(float f) {
    unsigned u = __float_as_uint(f);
    return (unsigned short)((u + 0x7FFFu + ((u >> 16) & 1u)) >> 16);
}

// ===========================================================================
// One-time conversion / precompute kernels (tiny)
// ===========================================================================
__global__ __launch_bounds__(256) void conv_bf16(
    const float* __restrict__ src, unsigned short* __restrict__ dst, int n8)
{
    int i = blockIdx.x * 256 + threadIdx.x;
    if (i >= n8) return;
    const float4* s = reinterpret_cast<const float4*>(src + (size_t)i * 8);
    float4 a = s[0], b = s[1];
    unsigned short o[8] = { bf16r(a.x), bf16r(a.y), bf16r(a.z), bf16r(a.w),
                            bf16r(b.x), bf16r(b.y), bf16r(b.z), bf16r(b.w) };
    *reinterpret_cast<uint4*>(dst + (size_t)i * 8) = *reinterpret_cast<uint4*>(o);
}

// table[c][u*4+g] = Wec[c] . Wihc[g*256+u] + bihc[g*256+u] + bhhc[g*256+u]  (f32)
__global__ __launch_bounds__(256) void build_table(
    const float* __restrict__ Wec, const float* __restrict__ Wihc,
    const float* __restrict__ bihc, const float* __restrict__ bhhc,
    float* __restrict__ table)
{
    int id = blockIdx.x * 256 + threadIdx.x;   // 26*1024
    if (id >= 26 * 1024) return;
    int c = id >> 10, rp = id & 1023;
    int u = rp >> 2, g = rp & 3, row = g * 256 + u;
    const float4* a = reinterpret_cast<const float4*>(Wec + (size_t)c * 256);
    const float4* b = reinterpret_cast<const float4*>(Wihc + (size_t)row * 256);
    float acc = 0.f;
    #pragma unroll 16
    for (int k = 0; k < 64; ++k) {
        float4 av = a[k], bv = b[k];
        acc += av.x * bv.x + av.y * bv.y + av.z * bv.z + av.w * bv.w;
    }
    table[id] = acc + bihc[row] + bhhc[row];
}

// Bhc[u*4+g][k] = bf16(Whhc[g*256+u][k])   [1024][256]
__global__ __launch_bounds__(256) void build_Bhc(
    const float* __restrict__ Whhc, unsigned short* __restrict__ Bhc)
{
    int id = blockIdx.x * 256 + threadIdx.x;   // 1024*32
    int rp = id >> 5, k8 = id & 31;
    int u = rp >> 2, g = rp & 3;
    const float4* sv = reinterpret_cast<const float4*>(
        Whhc + (size_t)(g * 256 + u) * 256 + k8 * 8);
    float4 a = sv[0], b = sv[1];
    unsigned short o[8] = { bf16r(a.x), bf16r(a.y), bf16r(a.z), bf16r(a.w),
                            bf16r(b.x), bf16r(b.y), bf16r(b.z), bf16r(b.w) };
    *reinterpret_cast<uint4*>(Bhc + (size_t)rp * 256 + k8 * 8) =
        *reinterpret_cast<uint4*>(o);
}

// Xw[s][k] = k<1024 ? bf16(Wemb[word_idx[s]][k]) : h_cb[s][k-1024]
__global__ __launch_bounds__(256) void build_Xw(
    const int* __restrict__ word_idx, const float* __restrict__ Wemb,
    const unsigned short* __restrict__ h_cb, unsigned short* __restrict__ Xw)
{
    int id = blockIdx.x * 256 + threadIdx.x;      // 4096*160
    int row = id / 160, c8 = id % 160;
    int k = c8 * 8;
    uint4 outv;
    if (k < 1024) {
        const float4* sv = reinterpret_cast<const float4*>(
            Wemb + (size_t)word_idx[row] * 1024 + k);
        float4 a = sv[0], b = sv[1];
        unsigned short o[8] = { bf16r(a.x), bf16r(a.y), bf16r(a.z), bf16r(a.w),
                                bf16r(b.x), bf16r(b.y), bf16r(b.z), bf16r(b.w) };
        outv = *reinterpret_cast<uint4*>(o);
    } else {
        outv = *reinterpret_cast<const uint4*>(h_cb + (size_t)row * 256 + (k - 1024));
    }
    *reinterpret_cast<uint4*>(Xw + (size_t)row * 1280 + k) = outv;
}

// ===========================================================================
// Fused char LSTM step: gates = h_in @ Bhc^T (MFMA) + table[cidx] ; cell ->
// h_out (bf16), c (f32). Tile 128 rows x 64 cols (=16 units). Grid (16,32).
// h ping-pong buffers avoid the cross-WG read/write race on h.
// ===========================================================================
__global__ __launch_bounds__(256) void char_step(
    const int* __restrict__ char_idx, int t,
    const unsigned short* __restrict__ Bhc,   // [1024][256]
    const float* __restrict__ table,          // [26][1024]
    const unsigned short* __restrict__ h_in,  // [4096][256] bf16
    unsigned short* __restrict__ h_out,       // [4096][256] bf16
    float* __restrict__ c_c)                  // [4096][256]
{
    __shared__ unsigned short As[128 * 64];   // 16 KB
    __shared__ unsigned short Bs[64 * 64];    // 8 KB
    __shared__ float gl[64 * 132];            // 33.8 KB, [col][row] pad 132
    __shared__ int cidx_s[128];

    const int tid  = threadIdx.x;
    const int lane = tid & 63;
    const int wm = (tid >> 6) >> 1, wn = (tid >> 6) & 1;
    const int fr = lane & 15, fk = lane >> 4;
    const int n0 = blockIdx.x * 64;           // gate-col base (16 units)
    const int m0 = blockIdx.y * 128;          // word-row base

    if (tid < 128) cidx_s[tid] = char_idx[(m0 + tid) * CLEN + t];

    uint4 ar[4], br[2];
    int rowa[4], kca[4], rowb[2], kcb[2];
    #pragma unroll
    for (int c = 0; c < 4; ++c) {
        int ch = c * 256 + tid;
        rowa[c] = ch >> 3; kca[c] = ch & 7;
    }
    #pragma unroll
    for (int c = 0; c < 2; ++c) {
        int ch = c * 256 + tid;
        rowb[c] = ch >> 3; kcb[c] = ch & 7;
    }

    auto load_tiles = [&](int k0) {
        #pragma unroll
        for (int c = 0; c < 4; ++c)
            ar[c] = *reinterpret_cast<const uint4*>(
                h_in + (size_t)(m0 + rowa[c]) * 256 + k0 + kca[c] * 8);
        #pragma unroll
        for (int c = 0; c < 2; ++c)
            br[c] = *reinterpret_cast<const uint4*>(
                Bhc + (size_t)(n0 + rowb[c]) * 256 + k0 + kcb[c] * 8);
    };

    f32x4 acc[4][2];
    #pragma unroll
    for (int i = 0; i < 4; ++i)
        #pragma unroll
        for (int j = 0; j < 2; ++j) acc[i][j] = f32x4{0.f, 0.f, 0.f, 0.f};

    load_tiles(0);
    for (int k0 = 0; k0 < 256; k0 += 64) {
        __syncthreads();
        #pragma unroll
        for (int c = 0; c < 4; ++c) {
            int sw = kca[c] ^ (rowa[c] & 7);
            *reinterpret_cast<uint4*>(&As[rowa[c] * 64 + sw * 8]) = ar[c];
        }
        #pragma unroll
        for (int c = 0; c < 2; ++c) {
            int sw = kcb[c] ^ (rowb[c] & 7);
            *reinterpret_cast<uint4*>(&Bs[rowb[c] * 64 + sw * 8]) = br[c];
        }
        __syncthreads();
        if (k0 + 64 < 256) load_tiles(k0 + 64);
        #pragma unroll
        for (int ks = 0; ks < 2; ++ks) {
            bf16x8 af[4], bfr[2];
            #pragma unroll
            for (int i = 0; i < 4; ++i) {
                int ra = wm * 64 + i * 16 + fr;
                af[i] = *reinterpret_cast<const bf16x8*>(
                    &As[ra * 64 + (((ks * 4 + fk) ^ (ra & 7)) << 3)]);
            }
            #pragma unroll
            for (int j = 0; j < 2; ++j) {
                int rb = wn * 32 + j * 16 + fr;
                bfr[j] = *reinterpret_cast<const bf16x8*>(
                    &Bs[rb * 64 + (((ks * 4 + fk) ^ (rb & 7)) << 3)]);
            }
            #pragma unroll
            for (int i = 0; i < 4; ++i)
                #pragma unroll
                for (int j = 0; j < 2; ++j)
                    acc[i][j] = __builtin_amdgcn_mfma_f32_16x16x32_bf16(
                        af[i], bfr[j], acc[i][j], 0, 0, 0);
        }
    }

    // gate preactivations -> LDS [col][row]
    #pragma unroll
    for (int i = 0; i < 4; ++i) {
        int row0 = wm * 64 + i * 16 + fk * 4;
        #pragma unroll
        for (int j = 0; j < 2; ++j) {
            int col = wn * 32 + j * 16 + fr;
            *reinterpret_cast<float4*>(&gl[col * 132 + row0]) =
                *reinterpret_cast<const float4*>(&acc[i][j]);
        }
    }
    __syncthreads();

    // cell update: thread = (srow, half), 8 units each
    const int srow = tid >> 1, half = tid & 1;
    const int s = m0 + srow;
    const int ug0 = (n0 >> 2) + half * 8;
    const float* tb = table + (size_t)cidx_s[srow] * 1024 + n0 + half * 32;
    float cv[8];
    *reinterpret_cast<float4*>(cv)     = *reinterpret_cast<const float4*>(c_c + (size_t)s * 256 + ug0);
    *reinterpret_cast<float4*>(cv + 4) = *reinterpret_cast<const float4*>(c_c + (size_t)s * 256 + ug0 + 4);
    unsigned short ho[8];
    #pragma unroll
    for (int k = 0; k < 8; ++k) {
        int uu = half * 8 + k;
        float4 tv = *reinterpret_cast<const float4*>(tb + k * 4);
        float gi_ = gl[(uu * 4 + 0) * 132 + srow] + tv.x;
        float gf_ = gl[(uu * 4 + 1) * 132 + srow] + tv.y;
        float gg_ = gl[(uu * 4 + 2) * 132 + srow] + tv.z;
        float go_ = gl[(uu * 4 + 3) * 132 + srow] + tv.w;
        float i_ = sigmoidf_(gi_), f_ = sigmoidf_(gf_);
        float g_ = tanh_fast(gg_), o_ = sigmoidf_(go_);
        float cn = f_ * cv[k] + i_ * g_;
        cv[k] = cn;
        ho[k] = bf16r(o_ * tanh_fast(cn));
    }
    *reinterpret_cast<float4*>(c_c + (size_t)s * 256 + ug0)     = *reinterpret_cast<float4*>(cv);
    *reinterpret_cast<float4*>(c_c + (size_t)s * 256 + ug0 + 4) = *reinterpret_cast<float4*>(cv + 4);
    *reinterpret_cast<uint4*>(h_out + (size_t)s * 256 + ug0) = *reinterpret_cast<uint4*>(ho);
}

// ===========================================================================
// Word input GEMM (unchanged): C = A[M][K] @ B[N][K]^T + bias0 + bias1
// ===========================================================================
__global__ __launch_bounds__(256) void gemm_bf16_bt(
    const unsigned short* __restrict__ A, const unsigned short* __restrict__ B,
    const float* __restrict__ bias0, const float* __restrict__ bias1,
    float* __restrict__ C, int M, int N, int K)
{
    __shared__ unsigned short As[128 * 64];
    __shared__ unsigned short Bs[128 * 64];
    const int tid  = threadIdx.x;
    const int lane = tid & 63;
    const int wm = (tid >> 6) >> 1, wn = (tid >> 6) & 1;
    const int fr = lane & 15, fk = lane >> 4;
    const int n0 = blockIdx.x * 128;
    const int m0 = blockIdx.y * 128;

    uint4 ar[4], br[4];
    int rowi[4], kci[4];
    #pragma unroll
    for (int c = 0; c < 4; ++c) {
        int ch = c * 256 + tid;
        rowi[c] = ch >> 3; kci[c] = ch & 7;
    }

    auto load_tiles = [&](int k0) {
        #pragma unroll
        for (int c = 0; c < 4; ++c) {
            ar[c] = *reinterpret_cast<const uint4*>(
                A + (size_t)(m0 + rowi[c]) * K + k0 + kci[c] * 8);
            br[c] = *reinterpret_cast<const uint4*>(
                B + (size_t)(n0 + rowi[c]) * K + k0 + kci[c] * 8);
        }
    };

    f32x4 acc[4][4];
    #pragma unroll
    for (int i = 0; i < 4; ++i)
        #pragma unroll
        for (int j = 0; j < 4; ++j) acc[i][j] = f32x4{0.f, 0.f, 0.f, 0.f};

    load_tiles(0);
    for (int k0 = 0; k0 < K; k0 += 64) {
        __syncthreads();
        #pragma unroll
        for (int c = 0; c < 4; ++c) {
            int sw = kci[c] ^ (rowi[c] & 7);
            *reinterpret_cast<uint4*>(&As[rowi[c] * 64 + sw * 8]) = ar[c];
            *reinterpret_cast<uint4*>(&Bs[rowi[c] * 64 + sw * 8]) = br[c];
        }
        __syncthreads();
        if (k0 + 64 < K) load_tiles(k0 + 64);
        #pragma unroll
        for (int ks = 0; ks < 2; ++ks) {
            bf16x8 af[4], bfr[4];
            #pragma unroll
            for (int i = 0; i < 4; ++i) {
                int ra = wm * 64 + i * 16 + fr;
                af[i] = *reinterpret_cast<const bf16x8*>(
                    &As[ra * 64 + (((ks * 4 + fk) ^ (ra & 7)) << 3)]);
                int rb = wn * 64 + i * 16 + fr;
                bfr[i] = *reinterpret_cast<const bf16x8*>(
                    &Bs[rb * 64 + (((ks * 4 + fk) ^ (rb & 7)) << 3)]);
            }
            #pragma unroll
            for (int i = 0; i < 4; ++i)
                #pragma unroll
                for (int j = 0; j < 4; ++j)
                    acc[i][j] = __builtin_amdgcn_mfma_f32_16x16x32_bf16(
                        af[i], bfr[j], acc[i][j], 0, 0, 0);
        }
    }

    const int colb = n0 + wn * 64 + fr;
    float bsum[4];
    #pragma unroll
    for (int j = 0; j < 4; ++j) bsum[j] = bias0[colb + j * 16] + bias1[colb + j * 16];
    #pragma unroll
    for (int i = 0; i < 4; ++i) {
        int row0 = m0 + wm * 64 + i * 16 + fk * 4;
        #pragma unroll
        for (int j = 0; j < 4; ++j) {
            int col = colb + j * 16;
            #pragma unroll
            for (int r = 0; r < 4; ++r)
                C[(size_t)(row0 + r) * N + col] = acc[i][j][r] + bsum[j];
        }
    }
}

// ---------------------------------------------------------------------------
// Word-level LSTM recurrence: per-XCD redundant groups, L2-local sc0 handoff.
// Only change from R5: writes packed-bf16 hs_b instead of f32 hs.
// ---------------------------------------------------------------------------
__global__ __launch_bounds__(256, 1) void word_rec(
    const float* __restrict__ precomp, const float* __restrict__ W_hh,
    unsigned* __restrict__ hs_b, unsigned* hdata, unsigned* hsum, int* xcd_ctr)
{
    const int tid  = threadIdx.x;
    const int v    = tid >> 6;
    const int lane = tid & 63;
    const int q    = lane >> 5;
    const int m    = lane & 31;
    const int j    = lane & 7;

    __shared__ int s_vals[2];
    if (tid == 0) {
        unsigned xcc;
        asm volatile("s_getreg_b32 %0, hwreg(HW_REG_XCC_ID)" : "=s"(xcc));
        xcc &= 7u;
        s_vals[0] = (int)xcc;
        s_vals[1] = atomicAdd(&xcd_ctr[xcc], 1);
    }
    __syncthreads();
    const int xcc  = s_vals[0];
    const int slot = s_vals[1];
    if (slot >= NSLOT) return;

    const int base_u = slot * 32 + v * 8;
    unsigned* hdata_x = hdata + xcc * 1024;
    unsigned* hsum_x  = hsum  + xcc * 256;

    h2_t wp[16][16];
    #pragma unroll
    for (int r = 0; r < 16; ++r) {
        const int grow = (2 * q + (r >> 3)) * 1024 + base_u + (r & 7);
        const float4* rp = reinterpret_cast<const float4*>(
            W_hh + (size_t)grow * 1024 + 32 * m);
        #pragma unroll
        for (int d = 0; d < 8; ++d) {
            float4 f = rp[d];
            wp[r][2 * d]     = __builtin_amdgcn_cvt_pkrtz(f.x, f.y);
            wp[r][2 * d + 1] = __builtin_amdgcn_cvt_pkrtz(f.z, f.w);
        }
    }

    float c_reg = 0.f;

    for (int t = 0; t < SLEN; ++t) {
        const int pp = (t + 1) & 1;
        const int pc = t & 1;

        float pre0 = 0.f, pre1 = 0.f, pre2 = 0.f, pre3 = 0.f;
        if (lane < 8) {
            const float* pr = precomp + (size_t)t * 4096 + base_u + j;
            pre0 = pr[0]; pre1 = pr[1024]; pre2 = pr[2048]; pre3 = pr[3072];
        }

        h2_t hp[16];
        if (t > 0) {
            const unsigned tgt = (unsigned)(t - 1);
            const unsigned* sp = hsum_x + pp * 128 + 4 * m;
            uv4 sv;
            int it = 0; bool dead = false;
            for (;;) {
                asm volatile("global_load_dwordx4 %0, %1, off sc0\n\t"
                             "s_waitcnt vmcnt(0)"
                             : "=&v"(sv) : "v"(sp) : "memory");
                bool ok = ((sv.x >> 16) == tgt) & ((sv.y >> 16) == tgt) &
                          ((sv.z >> 16) == tgt) & ((sv.w >> 16) == tgt);
                if (__all(ok)) break;
                if (++it > POLL_LIMIT) { dead = true; break; }
            }
            if (dead) return;

            const unsigned* dp = hdata_x + pp * 512 + 16 * m;
            uv4 d0, d1, d2, d3;
            asm volatile(
                "global_load_dwordx4 %0, %4, off sc0\n\t"
                "global_load_dwordx4 %1, %4, off offset:16 sc0\n\t"
                "global_load_dwordx4 %2, %4, off offset:32 sc0\n\t"
                "global_load_dwordx4 %3, %4, off offset:48 sc0\n\t"
                "s_waitcnt vmcnt(0)"
                : "=&v"(d0), "=&v"(d1), "=&v"(d2), "=&v"(d3)
                : "v"(dp) : "memory");
            hp[0]=bc_h2(d0.x);  hp[1]=bc_h2(d0.y);  hp[2]=bc_h2(d0.z);  hp[3]=bc_h2(d0.w);
            hp[4]=bc_h2(d1.x);  hp[5]=bc_h2(d1.y);  hp[6]=bc_h2(d1.z);  hp[7]=bc_h2(d1.w);
            hp[8]=bc_h2(d2.x);  hp[9]=bc_h2(d2.y);  hp[10]=bc_h2(d2.z); hp[11]=bc_h2(d2.w);
            hp[12]=bc_h2(d3.x); hp[13]=bc_h2(d3.y); hp[14]=bc_h2(d3.z); hp[15]=bc_h2(d3.w);
        } else {
            #pragma unroll
            for (int i = 0; i < 16; ++i) hp[i] = (h2_t)(__fp16)0;
        }

        float sel = 0.f;
        #pragma unroll
        for (int r = 0; r < 16; ++r) {
            float a0 = 0.f, a1 = 0.f, a2 = 0.f, a3 = 0.f;
            #pragma unroll
            for (int d = 0; d < 4; ++d) {
                a0 = __builtin_amdgcn_fdot2(wp[r][d],      hp[d],      a0, false);
                a1 = __builtin_amdgcn_fdot2(wp[r][4 + d],  hp[4 + d],  a1, false);
                a2 = __builtin_amdgcn_fdot2(wp[r][8 + d],  hp[8 + d],  a2, false);
                a3 = __builtin_amdgcn_fdot2(wp[r][12 + d], hp[12 + d], a3, false);
            }
            float s = (a0 + a1) + (a2 + a3);
            s += __shfl_xor(s, 1);  s += __shfl_xor(s, 2);
            s += __shfl_xor(s, 4);  s += __shfl_xor(s, 8);
            s += __shfl_xor(s, 16);
            sel = ((lane & 31) == r) ? s : sel;
        }

        const float gi = __shfl(sel, j);
        const float gf = __shfl(sel, 8 + j);
        const float gg = __shfl(sel, 32 + j);
        const float go = __shfl(sel, 40 + j);

        float h = 0.f;
        if (lane < 8) {
            const float i_ = sigmoidf_(gi + pre0);
            const float f_ = sigmoidf_(gf + pre1);
            const float g_ = tanh_fast(gg + pre2);
            const float o_ = sigmoidf_(go + pre3);
            c_reg = f_ * c_reg + i_ * g_;
            h = o_ * tanh_fast(c_reg);
        }

        const float hn = __shfl_down(h, 1);
        if (lane < 8 && (lane & 1) == 0) {
            // bf16 pair for the tag stage (plain cached store)
            unsigned pb = (unsigned)bf16r(h) | ((unsigned)bf16r(hn) << 16);
            hs_b[(size_t)t * 512 + (base_u >> 1) + (lane >> 1)] = pb;
            // fp16 pair for the L2-local handoff
            unsigned pk = __builtin_bit_cast(unsigned,
                              __builtin_amdgcn_cvt_pkrtz(h, hn));
            unsigned* dpw = hdata_x + pc * 512 + slot * 16 + v * 4 + (lane >> 1);
            asm volatile("global_store_dword %0, %1, off sc0"
                         :: "v"(dpw), "v"(pk) : "memory");
        }
        if (lane == 0) {
            unsigned tw = ((unsigned)t << 16) | (unsigned)slot;
            unsigned* spw = hsum_x + pc * 128 + slot * 4 + v;
            asm volatile("s_waitcnt vmcnt(0)\n\t"
                         "global_store_dword %0, %1, off sc0"
                         :: "v"(spw), "v"(tw) : "memory");
        }
    }
}

// ===========================================================================
// Tag projection (MFMA) + fused log_softmax. Grid 32, tile 128 rows x 64 tags.
// ===========================================================================
__global__ __launch_bounds__(256) void tag_mfma(
    const unsigned short* __restrict__ A,     // hs_b as bf16 [4096][1024]
    const unsigned short* __restrict__ B,     // Wtagb [64][1024]
    const float* __restrict__ btag, float* __restrict__ out)
{
    __shared__ unsigned short As[128 * 64];   // 16 KB
    __shared__ unsigned short Bs[64 * 64];    // 8 KB
    __shared__ float ts[128 * 65];            // 33.3 KB

    const int tid  = threadIdx.x;
    const int lane = tid & 63;
    const int wm = (tid >> 6) >> 1, wn = (tid >> 6) & 1;
    const int fr = lane & 15, fk = lane >> 4;
    const int m0 = blockIdx.x * 128;

    uint4 ar[4], br[2];
    int rowa[4], kca[4], rowb[2], kcb[2];
    #pragma unroll
    for (int c = 0; c < 4; ++c) {
        int ch = c * 256 + tid;
        rowa[c] = ch >> 3; kca[c] = ch & 7;
    }
    #pragma unroll
    for (int c = 0; c < 2; ++c) {
        int ch = c * 256 + tid;
        rowb[c] = ch >> 3; kcb[c] = ch & 7;
    }

    auto load_tiles = [&](int k0) {
        #pragma unroll
        for (int c = 0; c < 4; ++c)
            ar[c] = *reinterpret_cast<const uint4*>(
                A + (size_t)(m0 + rowa[c]) * 1024 + k0 + kca[c] * 8);
        #pragma unroll
        for (int c = 0; c < 2; ++c)
            br[c] = *reinterpret_cast<const uint4*>(
                B + (size_t)rowb[c] * 1024 + k0 + kcb[c] * 8);
    };

    f32x4 acc[4][2];
    #pragma unroll
    for (int i = 0; i < 4; ++i)
        #pragma unroll
        for (int j = 0; j < 2; ++j) acc[i][j] = f32x4{0.f, 0.f, 0.f, 0.f};

    load_tiles(0);
    for (int k0 = 0; k0 < 1024; k0 += 64) {
        __syncthreads();
        #pragma unroll
        for (int c = 0; c < 4; ++c) {
            int sw = kca[c] ^ (rowa[c] & 7);
            *reinterpret_cast<uint4*>(&As[rowa[c] * 64 + sw * 8]) = ar[c];
        }
        #pragma unroll
        for (int c = 0; c < 2; ++c) {
            int sw = kcb[c] ^ (rowb[c] & 7);
            *reinterpret_cast<uint4*>(&Bs[rowb[c] * 64 + sw * 8]) = br[c];
        }
        __syncthreads();
        if (k0 + 64 < 1024) load_tiles(k0 + 64);
        #pragma unroll
        for (int ks = 0; ks < 2; ++ks) {
            bf16x8 af[4], bfr[2];
            #pragma unroll
            for (int i = 0; i < 4; ++i) {
                int ra = wm * 64 + i * 16 + fr;
                af[i] = *reinterpret_cast<const bf16x8*>(
                    &As[ra * 64 + (((ks * 4 + fk) ^ (ra & 7)) << 3)]);
            }
            #pragma unroll
            for (int j = 0; j < 2; ++j) {
                int rb = wn * 32 + j * 16 + fr;
                bfr[j] = *reinterpret_cast<const bf16x8*>(
                    &Bs[rb * 64 + (((ks * 4 + fk) ^ (rb & 7)) << 3)]);
            }
            #pragma unroll
            for (int i = 0; i < 4; ++i)
                #pragma unroll
                for (int j = 0; j < 2; ++j)
                    acc[i][j] = __builtin_amdgcn_mfma_f32_16x16x32_bf16(
                        af[i], bfr[j], acc[i][j], 0, 0, 0);
        }
    }

    // tag_space tile -> LDS
    #pragma unroll
    for (int i = 0; i < 4; ++i) {
        int row0 = wm * 64 + i * 16 + fk * 4;
        #pragma unroll
        for (int j = 0; j < 2; ++j) {
            int col = wn * 32 + j * 16 + fr;
            float bt = btag[col];
            #pragma unroll
            for (int r = 0; r < 4; ++r)
                ts[(row0 + r) * 65 + col] = acc[i][j][r] + bt;
        }
    }
    __syncthreads();

    // log_softmax per row (128 rows, one thread each)
    if (tid < 128) {
        const float* rowp = ts + tid * 65;
        float mx = rowp[0];
        #pragma unroll 16
        for (int c = 1; c < 64; ++c) mx = fmaxf(mx, rowp[c]);
        float ssum = 0.f;
        #pragma unroll 16
        for (int c = 0; c < 64; ++c) ssum += __expf(rowp[c] - mx);
        const float lse = mx + logf(ssum);
        float* op = out + (size_t)(m0 + tid) * 64;
        #pragma unroll 16
        for (int c = 0; c < 64; ++c) op[c] = rowp[c] - lse;
    }
}

// ---------------------------------------------------------------------------
extern "C" void kernel_launch(void* const* d_in, const int* in_sizes, int n_in,
                              void* d_out, int out_size, void* d_ws, size_t ws_size,
                              hipStream_t stream)
{
    const int*   char_idx = (const int*)  d_in[0];
    const int*   word_idx = (const int*)  d_in[1];
    const float* Wemb     = (const float*)d_in[2];
    const float* Wec      = (const float*)d_in[3];
    const float* Wihc     = (const float*)d_in[4];
    const float* Whhc     = (const float*)d_in[5];
    const float* bihc     = (const float*)d_in[6];
    const float* bhhc     = (const float*)d_in[7];
    const float* Wih      = (const float*)d_in[8];
    const float* Whh      = (const float*)d_in[9];
    const float* bih      = (const float*)d_in[10];
    const float* bhh      = (const float*)d_in[11];
    const float* Wtag     = (const float*)d_in[12];
    const float* btag     = (const float*)d_in[13];
    float* out = (float*)d_out;

    // Workspace layout (~102 MB), all segments 16B-aligned
    char* w = (char*)d_ws;
    float*          precomp = (float*)w;            w += (size_t)SLEN * 4096 * 4;   // 64 MB
    unsigned short* Wihb    = (unsigned short*)w;   w += (size_t)4096 * 1280 * 2;   // 10.5 MB
    unsigned short* Xw      = (unsigned short*)w;   w += (size_t)4096 * 1280 * 2;   // 10.5 MB
    unsigned*       hs_b    = (unsigned*)w;         w += (size_t)SLEN * 512 * 4;    // 8 MB
    float*          c_c     = (float*)w;            w += (size_t)SLEN * HCD * 4;    // 4 MB
    unsigned short* hb0     = (unsigned short*)w;   w += (size_t)SLEN * HCD * 2;    // 2 MB
    unsigned short* hb1     = (unsigned short*)w;   w += (size_t)SLEN * HCD * 2;    // 2 MB
    unsigned short* Bhc     = (unsigned short*)w;   w += (size_t)1024 * 256 * 2;    // 512 KB
    float*          table   = (float*)w;            w += 26 * 1024 * 4 + 1920;      // ~128 KB
    unsigned short* Wtagb   = (unsigned short*)w;   w += (size_t)64 * 1024 * 2;     // 128 KB
    unsigned*       hdata   = (unsigned*)w;         w += 8 * 1024 * 4;
    unsigned*       hsum    = (unsigned*)w;         w += 8 * 256 * 4;
    int*            xcd_ctr = (int*)w;

    (void)hipMemsetAsync(c_c, 0, (size_t)SLEN * HCD * sizeof(float), stream);
    (void)hipMemsetAsync(hb0, 0, (size_t)SLEN * HCD * sizeof(unsigned short), stream);
    (void)hipMemsetAsync(hsum, 0xFF, 8 * 256 * sizeof(unsigned), stream);
    (void)hipMemsetAsync(xcd_ctr, 0, 8 * sizeof(int), stream);

    // --- one-time conversions / tables ---
    build_table<<<104, 256, 0, stream>>>(Wec, Wihc, bihc, bhhc, table);
    build_Bhc<<<128, 256, 0, stream>>>(Whhc, Bhc);
    conv_bf16<<<2560, 256, 0, stream>>>(Wih, Wihb, 4096 * 1280 / 8);
    conv_bf16<<<32, 256, 0, stream>>>(Wtag, Wtagb, 64 * 1024 / 8);

    // --- char-level LSTM: 12 fused MFMA+cell steps (h ping-pong) ---
    unsigned short* hbufs[2] = { hb0, hb1 };
    for (int t = 0; t < CLEN; ++t) {
        char_step<<<dim3(16, 32), 256, 0, stream>>>(
            char_idx, t, Bhc, table, hbufs[t & 1], hbufs[(t + 1) & 1], c_c);
    }
    // final h_char is in hb0 (12 even)

    // --- word input projection ---
    build_Xw<<<SLEN * 160 / 256, 256, 0, stream>>>(word_idx, Wemb, hb0, Xw);
    gemm_bf16_bt<<<dim3(32, 32), 256, 0, stream>>>(
        Xw, Wihb, bih, bhh, precomp, SLEN, 4096, 1280);

    // --- sequential word-level LSTM recurrence (per-XCD redundant) ---
    word_rec<<<256, 256, 0, stream>>>(precomp, Whh, hs_b, hdata, hsum, xcd_ctr);

    // --- tag projection + log_softmax ---
    tag_mfma<<<32, 256, 0, stream>>>(
        (const unsigned short*)hs_b, Wtagb, btag, out);
}

// Round 7
// 1531.884 us; speedup vs baseline: 66.1528x; 1.1386x over previous
//
#include <hip/hip_runtime.h>
#include <hip/hip_bf16.h>

// Dims (fixed by the reference)
#define SLEN 4096
#define CLEN 12
#define ECD  256
#define HCD  256
#define ED   1024
#define HD   1024
#define TD   64
#define NSLOT 32          // WGs per XCD group (32 units each)
#define POLL_LIMIT 8192   // bailout for underfilled groups

typedef __fp16 h2_t __attribute__((ext_vector_type(2)));
typedef unsigned  uv4 __attribute__((ext_vector_type(4)));
typedef __attribute__((ext_vector_type(8))) short bf16x8;   // MFMA A/B frag
typedef __attribute__((ext_vector_type(4))) float f32x4;    // MFMA C/D frag

__device__ __forceinline__ float sigmoidf_(float x) { return 1.f / (1.f + __expf(-x)); }
__device__ __forceinline__ float tanh_fast(float x) {
    float ax = fabsf(x);
    float e = __expf(2.f * ax);          // inf-safe
    float t = 1.f - 2.f / (e + 1.f);
    return copysignf(t, x);
}
__device__ __forceinline__ h2_t bc_h2(unsigned u) { return __builtin_bit_cast(h2_t, u); }
__device__ __forceinline__ unsigned short bf16r(float f) {
    unsigned u = __float_as_uint(f);
    return (unsigned short)((u + 0x7FFFu + ((u >> 16) & 1u)) >> 16);
}

// ===========================================================================
// One-time conversion / precompute kernels (tiny)
// ===========================================================================
__global__ __launch_bounds__(256) void conv_bf16(
    const float* __restrict__ src, unsigned short* __restrict__ dst, int n8)
{
    int i = blockIdx.x * 256 + threadIdx.x;
    if (i >= n8) return;
    const float4* s = reinterpret_cast<const float4*>(src + (size_t)i * 8);
    float4 a = s[0], b = s[1];
    unsigned short o[8] = { bf16r(a.x), bf16r(a.y), bf16r(a.z), bf16r(a.w),
                            bf16r(b.x), bf16r(b.y), bf16r(b.z), bf16r(b.w) };
    *reinterpret_cast<uint4*>(dst + (size_t)i * 8) = *reinterpret_cast<uint4*>(o);
}

// table[c][u*4+g] = Wec[c] . Wihc[g*256+u] + bihc[g*256+u] + bhhc[g*256+u]  (f32)
__global__ __launch_bounds__(256) void build_table(
    const float* __restrict__ Wec, const float* __restrict__ Wihc,
    const float* __restrict__ bihc, const float* __restrict__ bhhc,
    float* __restrict__ table)
{
    int id = blockIdx.x * 256 + threadIdx.x;   // 26*1024
    if (id >= 26 * 1024) return;
    int c = id >> 10, rp = id & 1023;
    int u = rp >> 2, g = rp & 3, row = g * 256 + u;
    const float4* a = reinterpret_cast<const float4*>(Wec + (size_t)c * 256);
    const float4* b = reinterpret_cast<const float4*>(Wihc + (size_t)row * 256);
    float acc = 0.f;
    #pragma unroll 16
    for (int k = 0; k < 64; ++k) {
        float4 av = a[k], bv = b[k];
        acc += av.x * bv.x + av.y * bv.y + av.z * bv.z + av.w * bv.w;
    }
    table[id] = acc + bihc[row] + bhhc[row];
}

// Wt[(kg*1024 + C)*8 + e] = bf16(Whhc[row][kg*8+e])
// C = h*512 + g*128 + ul  -> row = g*256 + h*128 + ul   (gate-blocked cols)
__global__ __launch_bounds__(256) void build_Wt(
    const float* __restrict__ Whhc, unsigned short* __restrict__ Wt)
{
    int id = blockIdx.x * 256 + threadIdx.x;   // 1024 * 32
    int C = id >> 5, kg = id & 31;
    int h = C >> 9, rem = C & 511, g = rem >> 7, ul = rem & 127;
    int row = g * 256 + h * 128 + ul;
    const float4* sv = reinterpret_cast<const float4*>(
        Whhc + (size_t)row * 256 + kg * 8);
    float4 a = sv[0], b = sv[1];
    unsigned short o[8] = { bf16r(a.x), bf16r(a.y), bf16r(a.z), bf16r(a.w),
                            bf16r(b.x), bf16r(b.y), bf16r(b.z), bf16r(b.w) };
    *reinterpret_cast<uint4*>(Wt + (size_t)(kg * 1024 + C) * 8) =
        *reinterpret_cast<uint4*>(o);
}

// Xw[s][k] = k<1024 ? bf16(Wemb[word_idx[s]][k]) : h_cb[s][k-1024]
__global__ __launch_bounds__(256) void build_Xw(
    const int* __restrict__ word_idx, const float* __restrict__ Wemb,
    const unsigned short* __restrict__ h_cb, unsigned short* __restrict__ Xw)
{
    int id = blockIdx.x * 256 + threadIdx.x;      // 4096*160
    int row = id / 160, c8 = id % 160;
    int k = c8 * 8;
    uint4 outv;
    if (k < 1024) {
        const float4* sv = reinterpret_cast<const float4*>(
            Wemb + (size_t)word_idx[row] * 1024 + k);
        float4 a = sv[0], b = sv[1];
        unsigned short o[8] = { bf16r(a.x), bf16r(a.y), bf16r(a.z), bf16r(a.w),
                                bf16r(b.x), bf16r(b.y), bf16r(b.z), bf16r(b.w) };
        outv = *reinterpret_cast<uint4*>(o);
    } else {
        outv = *reinterpret_cast<const uint4*>(h_cb + (size_t)row * 256 + (k - 1024));
    }
    *reinterpret_cast<uint4*>(Xw + (size_t)row * 1280 + k) = outv;
}

// ===========================================================================
// Fused char LSTM: ALL 12 steps in one kernel. 128 WGs x 32 words each.
// Words are independent -> no cross-WG sync. h ping-pong in LDS (swizzled),
// c in registers, W streamed from L2 via k-major Wt, gates land so that each
// lane owns complete (word,unit) gate quads -> zero cross-lane cell update.
// ===========================================================================
__global__ __launch_bounds__(256) void char_fused(
    const int* __restrict__ char_idx,
    const unsigned short* __restrict__ Wt,   // [32 kg][1024 C][8] bf16
    const float* __restrict__ table,         // [26][1024]
    unsigned short* __restrict__ h_cb)       // out [4096][256] bf16
{
    __shared__ unsigned short hA[2][8192];   // 2 x [32 words][256] bf16, swizzled
    __shared__ int cidx_s[32 * CLEN];

    const int tid  = threadIdx.x;
    const int lane = tid & 63;
    const int wv   = tid >> 6;       // wave 0..3
    const int fr   = lane & 15;
    const int fkq  = lane >> 4;      // 0..3
    const int w0   = blockIdx.x * 32;

    for (int e = tid; e < 32 * CLEN; e += 256)
        cidx_s[e] = char_idx[(w0 + (e / CLEN)) * CLEN + (e % CLEN)];
    {   // zero hA[0] (h_{-1} = 0)
        uint4 z; z.x = z.y = z.z = z.w = 0u;
        for (int e = tid; e < 1024; e += 256)
            *reinterpret_cast<uint4*>(&hA[0][e * 8]) = z;
    }
    __syncthreads();

    float cst[32];
    #pragma unroll
    for (int i = 0; i < 32; ++i) cst[i] = 0.f;

    for (int t = 0; t < CLEN; ++t) {
        const int cur = t & 1, nxt = cur ^ 1;
        #pragma unroll
        for (int h = 0; h < 2; ++h) {
            f32x4 acc[2][8];
            #pragma unroll
            for (int m = 0; m < 2; ++m)
                #pragma unroll
                for (int i = 0; i < 8; ++i) acc[m][i] = f32x4{0.f, 0.f, 0.f, 0.f};

            #pragma unroll
            for (int k0i = 0; k0i < 8; ++k0i) {
                const int kg = k0i * 4 + fkq;
                bf16x8 af[2];
                #pragma unroll
                for (int m = 0; m < 2; ++m) {
                    const int row = m * 16 + fr;
                    af[m] = *reinterpret_cast<const bf16x8*>(
                        &hA[cur][row * 256 + ((kg ^ ((row & 7) << 2)) << 3)]);
                }
                #pragma unroll
                for (int i = 0; i < 8; ++i) {
                    const int T = wv + (i << 2);               // tile 0..31
                    const int col = h * 512 + T * 16 + fr;     // gate-blocked col
                    const bf16x8 bf = *reinterpret_cast<const bf16x8*>(
                        Wt + (size_t)(kg * 1024 + col) * 8);
                    acc[0][i] = __builtin_amdgcn_mfma_f32_16x16x32_bf16(
                        af[0], bf, acc[0][i], 0, 0, 0);
                    acc[1][i] = __builtin_amdgcn_mfma_f32_16x16x32_bf16(
                        af[1], bf, acc[1][i], 0, 0, 0);
                }
            }

            // cell update: lane owns gates of 2 units x 8 words (i = 2g + ab)
            #pragma unroll
            for (int m = 0; m < 2; ++m) {
                #pragma unroll
                for (int r = 0; r < 4; ++r) {
                    const int wl = m * 16 + (lane >> 4) * 4 + r;  // word local
                    const int ci = cidx_s[wl * CLEN + t];
                    #pragma unroll
                    for (int ab = 0; ab < 2; ++ab) {
                        const int u = h * 128 + (wv + 4 * ab) * 16 + fr; // unit
                        const float4 tv = *reinterpret_cast<const float4*>(
                            table + (size_t)ci * 1024 + u * 4);
                        const int cix = ((h * 2 + m) * 2 + ab) * 4 + r;
                        const float gi_ = acc[m][0 + ab][r] + tv.x;
                        const float gf_ = acc[m][2 + ab][r] + tv.y;
                        const float gg_ = acc[m][4 + ab][r] + tv.z;
                        const float go_ = acc[m][6 + ab][r] + tv.w;
                        const float i_ = sigmoidf_(gi_), f_ = sigmoidf_(gf_);
                        const float g_ = tanh_fast(gg_), o_ = sigmoidf_(go_);
                        const float cn = f_ * cst[cix] + i_ * g_;
                        cst[cix] = cn;
                        const unsigned short hb = bf16r(o_ * tanh_fast(cn));
                        const int chn = u >> 3;
                        hA[nxt][wl * 256 + ((chn ^ ((wl & 7) << 2)) << 3) + (u & 7)] = hb;
                    }
                }
            }
        }
        __syncthreads();   // hA[nxt] complete before next step's GEMM
    }

    // final h (12 steps -> buffer 0) -> global, de-swizzled
    for (int e = tid; e < 1024; e += 256) {
        const int w = e >> 5, ch = e & 31;
        uint4 v = *reinterpret_cast<uint4*>(
            &hA[0][w * 256 + ((ch ^ ((w & 7) << 2)) << 3)]);
        *reinterpret_cast<uint4*>(h_cb + (size_t)(w0 + w) * 256 + ch * 8) = v;
    }
}

// ===========================================================================
// Word input GEMM (unchanged): C = A[M][K] @ B[N][K]^T + bias0 + bias1
// ===========================================================================
__global__ __launch_bounds__(256) void gemm_bf16_bt(
    const unsigned short* __restrict__ A, const unsigned short* __restrict__ B,
    const float* __restrict__ bias0, const float* __restrict__ bias1,
    float* __restrict__ C, int M, int N, int K)
{
    __shared__ unsigned short As[128 * 64];
    __shared__ unsigned short Bs[128 * 64];
    const int tid  = threadIdx.x;
    const int lane = tid & 63;
    const int wm = (tid >> 6) >> 1, wn = (tid >> 6) & 1;
    const int fr = lane & 15, fk = lane >> 4;
    const int n0 = blockIdx.x * 128;
    const int m0 = blockIdx.y * 128;

    uint4 ar[4], br[4];
    int rowi[4], kci[4];
    #pragma unroll
    for (int c = 0; c < 4; ++c) {
        int ch = c * 256 + tid;
        rowi[c] = ch >> 3; kci[c] = ch & 7;
    }

    auto load_tiles = [&](int k0) {
        #pragma unroll
        for (int c = 0; c < 4; ++c) {
            ar[c] = *reinterpret_cast<const uint4*>(
                A + (size_t)(m0 + rowi[c]) * K + k0 + kci[c] * 8);
            br[c] = *reinterpret_cast<const uint4*>(
                B + (size_t)(n0 + rowi[c]) * K + k0 + kci[c] * 8);
        }
    };

    f32x4 acc[4][4];
    #pragma unroll
    for (int i = 0; i < 4; ++i)
        #pragma unroll
        for (int j = 0; j < 4; ++j) acc[i][j] = f32x4{0.f, 0.f, 0.f, 0.f};

    load_tiles(0);
    for (int k0 = 0; k0 < K; k0 += 64) {
        __syncthreads();
        #pragma unroll
        for (int c = 0; c < 4; ++c) {
            int sw = kci[c] ^ (rowi[c] & 7);
            *reinterpret_cast<uint4*>(&As[rowi[c] * 64 + sw * 8]) = ar[c];
            *reinterpret_cast<uint4*>(&Bs[rowi[c] * 64 + sw * 8]) = br[c];
        }
        __syncthreads();
        if (k0 + 64 < K) load_tiles(k0 + 64);
        #pragma unroll
        for (int ks = 0; ks < 2; ++ks) {
            bf16x8 af[4], bfr[4];
            #pragma unroll
            for (int i = 0; i < 4; ++i) {
                int ra = wm * 64 + i * 16 + fr;
                af[i] = *reinterpret_cast<const bf16x8*>(
                    &As[ra * 64 + (((ks * 4 + fk) ^ (ra & 7)) << 3)]);
                int rb = wn * 64 + i * 16 + fr;
                bfr[i] = *reinterpret_cast<const bf16x8*>(
                    &Bs[rb * 64 + (((ks * 4 + fk) ^ (rb & 7)) << 3)]);
            }
            #pragma unroll
            for (int i = 0; i < 4; ++i)
                #pragma unroll
                for (int j = 0; j < 4; ++j)
                    acc[i][j] = __builtin_amdgcn_mfma_f32_16x16x32_bf16(
                        af[i], bfr[j], acc[i][j], 0, 0, 0);
        }
    }

    const int colb = n0 + wn * 64 + fr;
    float bsum[4];
    #pragma unroll
    for (int j = 0; j < 4; ++j) bsum[j] = bias0[colb + j * 16] + bias1[colb + j * 16];
    #pragma unroll
    for (int i = 0; i < 4; ++i) {
        int row0 = m0 + wm * 64 + i * 16 + fk * 4;
        #pragma unroll
        for (int j = 0; j < 4; ++j) {
            int col = colb + j * 16;
            #pragma unroll
            for (int r = 0; r < 4; ++r)
                C[(size_t)(row0 + r) * N + col] = acc[i][j][r] + bsum[j];
        }
    }
}

// ---------------------------------------------------------------------------
// Word-level LSTM recurrence (unchanged): per-XCD redundant groups,
// L2-local sc0 handoff, register-resident fp16 W_hh.
// ---------------------------------------------------------------------------
__global__ __launch_bounds__(256, 1) void word_rec(
    const float* __restrict__ precomp, const float* __restrict__ W_hh,
    unsigned* __restrict__ hs_b, unsigned* hdata, unsigned* hsum, int* xcd_ctr)
{
    const int tid  = threadIdx.x;
    const int v    = tid >> 6;
    const int lane = tid & 63;
    const int q    = lane >> 5;
    const int m    = lane & 31;
    const int j    = lane & 7;

    __shared__ int s_vals[2];
    if (tid == 0) {
        unsigned xcc;
        asm volatile("s_getreg_b32 %0, hwreg(HW_REG_XCC_ID)" : "=s"(xcc));
        xcc &= 7u;
        s_vals[0] = (int)xcc;
        s_vals[1] = atomicAdd(&xcd_ctr[xcc], 1);
    }
    __syncthreads();
    const int xcc  = s_vals[0];
    const int slot = s_vals[1];
    if (slot >= NSLOT) return;

    const int base_u = slot * 32 + v * 8;
    unsigned* hdata_x = hdata + xcc * 1024;
    unsigned* hsum_x  = hsum  + xcc * 256;

    h2_t wp[16][16];
    #pragma unroll
    for (int r = 0; r < 16; ++r) {
        const int grow = (2 * q + (r >> 3)) * 1024 + base_u + (r & 7);
        const float4* rp = reinterpret_cast<const float4*>(
            W_hh + (size_t)grow * 1024 + 32 * m);
        #pragma unroll
        for (int d = 0; d < 8; ++d) {
            float4 f = rp[d];
            wp[r][2 * d]     = __builtin_amdgcn_cvt_pkrtz(f.x, f.y);
            wp[r][2 * d + 1] = __builtin_amdgcn_cvt_pkrtz(f.z, f.w);
        }
    }

    float c_reg = 0.f;

    for (int t = 0; t < SLEN; ++t) {
        const int pp = (t + 1) & 1;
        const int pc = t & 1;

        float pre0 = 0.f, pre1 = 0.f, pre2 = 0.f, pre3 = 0.f;
        if (lane < 8) {
            const float* pr = precomp + (size_t)t * 4096 + base_u + j;
            pre0 = pr[0]; pre1 = pr[1024]; pre2 = pr[2048]; pre3 = pr[3072];
        }

        h2_t hp[16];
        if (t > 0) {
            const unsigned tgt = (unsigned)(t - 1);
            const unsigned* sp = hsum_x + pp * 128 + 4 * m;
            uv4 sv;
            int it = 0; bool dead = false;
            for (;;) {
                asm volatile("global_load_dwordx4 %0, %1, off sc0\n\t"
                             "s_waitcnt vmcnt(0)"
                             : "=&v"(sv) : "v"(sp) : "memory");
                bool ok = ((sv.x >> 16) == tgt) & ((sv.y >> 16) == tgt) &
                          ((sv.z >> 16) == tgt) & ((sv.w >> 16) == tgt);
                if (__all(ok)) break;
                if (++it > POLL_LIMIT) { dead = true; break; }
            }
            if (dead) return;

            const unsigned* dp = hdata_x + pp * 512 + 16 * m;
            uv4 d0, d1, d2, d3;
            asm volatile(
                "global_load_dwordx4 %0, %4, off sc0\n\t"
                "global_load_dwordx4 %1, %4, off offset:16 sc0\n\t"
                "global_load_dwordx4 %2, %4, off offset:32 sc0\n\t"
                "global_load_dwordx4 %3, %4, off offset:48 sc0\n\t"
                "s_waitcnt vmcnt(0)"
                : "=&v"(d0), "=&v"(d1), "=&v"(d2), "=&v"(d3)
                : "v"(dp) : "memory");
            hp[0]=bc_h2(d0.x);  hp[1]=bc_h2(d0.y);  hp[2]=bc_h2(d0.z);  hp[3]=bc_h2(d0.w);
            hp[4]=bc_h2(d1.x);  hp[5]=bc_h2(d1.y);  hp[6]=bc_h2(d1.z);  hp[7]=bc_h2(d1.w);
            hp[8]=bc_h2(d2.x);  hp[9]=bc_h2(d2.y);  hp[10]=bc_h2(d2.z); hp[11]=bc_h2(d2.w);
            hp[12]=bc_h2(d3.x); hp[13]=bc_h2(d3.y); hp[14]=bc_h2(d3.z); hp[15]=bc_h2(d3.w);
        } else {
            #pragma unroll
            for (int i = 0; i < 16; ++i) hp[i] = (h2_t)(__fp16)0;
        }

        float sel = 0.f;
        #pragma unroll
        for (int r = 0; r < 16; ++r) {
            float a0 = 0.f, a1 = 0.f, a2 = 0.f, a3 = 0.f;
            #pragma unroll
            for (int d = 0; d < 4; ++d) {
                a0 = __builtin_amdgcn_fdot2(wp[r][d],      hp[d],      a0, false);
                a1 = __builtin_amdgcn_fdot2(wp[r][4 + d],  hp[4 + d],  a1, false);
                a2 = __builtin_amdgcn_fdot2(wp[r][8 + d],  hp[8 + d],  a2, false);
                a3 = __builtin_amdgcn_fdot2(wp[r][12 + d], hp[12 + d], a3, false);
            }
            float s = (a0 + a1) + (a2 + a3);
            s += __shfl_xor(s, 1);  s += __shfl_xor(s, 2);
            s += __shfl_xor(s, 4);  s += __shfl_xor(s, 8);
            s += __shfl_xor(s, 16);
            sel = ((lane & 31) == r) ? s : sel;
        }

        const float gi = __shfl(sel, j);
        const float gf = __shfl(sel, 8 + j);
        const float gg = __shfl(sel, 32 + j);
        const float go = __shfl(sel, 40 + j);

        float h = 0.f;
        if (lane < 8) {
            const float i_ = sigmoidf_(gi + pre0);
            const float f_ = sigmoidf_(gf + pre1);
            const float g_ = tanh_fast(gg + pre2);
            const float o_ = sigmoidf_(go + pre3);
            c_reg = f_ * c_reg + i_ * g_;
            h = o_ * tanh_fast(c_reg);
        }

        const float hn = __shfl_down(h, 1);
        if (lane < 8 && (lane & 1) == 0) {
            unsigned pb = (unsigned)bf16r(h) | ((unsigned)bf16r(hn) << 16);
            hs_b[(size_t)t * 512 + (base_u >> 1) + (lane >> 1)] = pb;
            unsigned pk = __builtin_bit_cast(unsigned,
                              __builtin_amdgcn_cvt_pkrtz(h, hn));
            unsigned* dpw = hdata_x + pc * 512 + slot * 16 + v * 4 + (lane >> 1);
            asm volatile("global_store_dword %0, %1, off sc0"
                         :: "v"(dpw), "v"(pk) : "memory");
        }
        if (lane == 0) {
            unsigned tw = ((unsigned)t << 16) | (unsigned)slot;
            unsigned* spw = hsum_x + pc * 128 + slot * 4 + v;
            asm volatile("s_waitcnt vmcnt(0)\n\t"
                         "global_store_dword %0, %1, off sc0"
                         :: "v"(spw), "v"(tw) : "memory");
        }
    }
}

// ===========================================================================
// Tag projection (MFMA) + fused log_softmax (unchanged).
// ===========================================================================
__global__ __launch_bounds__(256) void tag_mfma(
    const unsigned short* __restrict__ A,     // hs_b as bf16 [4096][1024]
    const unsigned short* __restrict__ B,     // Wtagb [64][1024]
    const float* __restrict__ btag, float* __restrict__ out)
{
    __shared__ unsigned short As[128 * 64];
    __shared__ unsigned short Bs[64 * 64];
    __shared__ float ts[128 * 65];

    const int tid  = threadIdx.x;
    const int lane = tid & 63;
    const int wm = (tid >> 6) >> 1, wn = (tid >> 6) & 1;
    const int fr = lane & 15, fk = lane >> 4;
    const int m0 = blockIdx.x * 128;

    uint4 ar[4], br[2];
    int rowa[4], kca[4], rowb[2], kcb[2];
    #pragma unroll
    for (int c = 0; c < 4; ++c) {
        int ch = c * 256 + tid;
        rowa[c] = ch >> 3; kca[c] = ch & 7;
    }
    #pragma unroll
    for (int c = 0; c < 2; ++c) {
        int ch = c * 256 + tid;
        rowb[c] = ch >> 3; kcb[c] = ch & 7;
    }

    auto load_tiles = [&](int k0) {
        #pragma unroll
        for (int c = 0; c < 4; ++c)
            ar[c] = *reinterpret_cast<const uint4*>(
                A + (size_t)(m0 + rowa[c]) * 1024 + k0 + kca[c] * 8);
        #pragma unroll
        for (int c = 0; c < 2; ++c)
            br[c] = *reinterpret_cast<const uint4*>(
                B + (size_t)rowb[c] * 1024 + k0 + kcb[c] * 8);
    };

    f32x4 acc[4][2];
    #pragma unroll
    for (int i = 0; i < 4; ++i)
        #pragma unroll
        for (int j = 0; j < 2; ++j) acc[i][j] = f32x4{0.f, 0.f, 0.f, 0.f};

    load_tiles(0);
    for (int k0 = 0; k0 < 1024; k0 += 64) {
        __syncthreads();
        #pragma unroll
        for (int c = 0; c < 4; ++c) {
            int sw = kca[c] ^ (rowa[c] & 7);
            *reinterpret_cast<uint4*>(&As[rowa[c] * 64 + sw * 8]) = ar[c];
        }
        #pragma unroll
        for (int c = 0; c < 2; ++c) {
            int sw = kcb[c] ^ (rowb[c] & 7);
            *reinterpret_cast<uint4*>(&Bs[rowb[c] * 64 + sw * 8]) = br[c];
        }
        __syncthreads();
        if (k0 + 64 < 1024) load_tiles(k0 + 64);
        #pragma unroll
        for (int ks = 0; ks < 2; ++ks) {
            bf16x8 af[4], bfr[2];
            #pragma unroll
            for (int i = 0; i < 4; ++i) {
                int ra = wm * 64 + i * 16 + fr;
                af[i] = *reinterpret_cast<const bf16x8*>(
                    &As[ra * 64 + (((ks * 4 + fk) ^ (ra & 7)) << 3)]);
            }
            #pragma unroll
            for (int j = 0; j < 2; ++j) {
                int rb = wn * 32 + j * 16 + fr;
                bfr[j] = *reinterpret_cast<const bf16x8*>(
                    &Bs[rb * 64 + (((ks * 4 + fk) ^ (rb & 7)) << 3)]);
            }
            #pragma unroll
            for (int i = 0; i < 4; ++i)
                #pragma unroll
                for (int j = 0; j < 2; ++j)
                    acc[i][j] = __builtin_amdgcn_mfma_f32_16x16x32_bf16(
                        af[i], bfr[j], acc[i][j], 0, 0, 0);
        }
    }

    #pragma unroll
    for (int i = 0; i < 4; ++i) {
        int row0 = wm * 64 + i * 16 + fk * 4;
        #pragma unroll
        for (int j = 0; j < 2; ++j) {
            int col = wn * 32 + j * 16 + fr;
            float bt = btag[col];
            #pragma unroll
            for (int r = 0; r < 4; ++r)
                ts[(row0 + r) * 65 + col] = acc[i][j][r] + bt;
        }
    }
    __syncthreads();

    if (tid < 128) {
        const float* rowp = ts + tid * 65;
        float mx = rowp[0];
        #pragma unroll 16
        for (int c = 1; c < 64; ++c) mx = fmaxf(mx, rowp[c]);
        float ssum = 0.f;
        #pragma unroll 16
        for (int c = 0; c < 64; ++c) ssum += __expf(rowp[c] - mx);
        const float lse = mx + logf(ssum);
        float* op = out + (size_t)(m0 + tid) * 64;
        #pragma unroll 16
        for (int c = 0; c < 64; ++c) op[c] = rowp[c] - lse;
    }
}

// ---------------------------------------------------------------------------
extern "C" void kernel_launch(void* const* d_in, const int* in_sizes, int n_in,
                              void* d_out, int out_size, void* d_ws, size_t ws_size,
                              hipStream_t stream)
{
    const int*   char_idx = (const int*)  d_in[0];
    const int*   word_idx = (const int*)  d_in[1];
    const float* Wemb     = (const float*)d_in[2];
    const float* Wec      = (const float*)d_in[3];
    const float* Wihc     = (const float*)d_in[4];
    const float* Whhc     = (const float*)d_in[5];
    const float* bihc     = (const float*)d_in[6];
    const float* bhhc     = (const float*)d_in[7];
    const float* Wih      = (const float*)d_in[8];
    const float* Whh      = (const float*)d_in[9];
    const float* bih      = (const float*)d_in[10];
    const float* bhh      = (const float*)d_in[11];
    const float* Wtag     = (const float*)d_in[12];
    const float* btag     = (const float*)d_in[13];
    float* out = (float*)d_out;

    // Workspace layout (~94 MB), all segments 16B-aligned
    char* w = (char*)d_ws;
    float*          precomp = (float*)w;            w += (size_t)SLEN * 4096 * 4;   // 64 MB
    unsigned short* Wihb    = (unsigned short*)w;   w += (size_t)4096 * 1280 * 2;   // 10.5 MB
    unsigned short* Xw      = (unsigned short*)w;   w += (size_t)4096 * 1280 * 2;   // 10.5 MB
    unsigned*       hs_b    = (unsigned*)w;         w += (size_t)SLEN * 512 * 4;    // 8 MB
    unsigned short* h_cb    = (unsigned short*)w;   w += (size_t)SLEN * HCD * 2;    // 2 MB
    unsigned short* Wt      = (unsigned short*)w;   w += (size_t)32 * 1024 * 8 * 2; // 512 KB
    float*          table   = (float*)w;            w += 26 * 1024 * 4 + 1920;      // ~106 KB
    unsigned short* Wtagb   = (unsigned short*)w;   w += (size_t)64 * 1024 * 2;     // 128 KB
    unsigned*       hdata   = (unsigned*)w;         w += 8 * 1024 * 4;
    unsigned*       hsum    = (unsigned*)w;         w += 8 * 256 * 4;
    int*            xcd_ctr = (int*)w;

    (void)hipMemsetAsync(hsum, 0xFF, 8 * 256 * sizeof(unsigned), stream);
    (void)hipMemsetAsync(xcd_ctr, 0, 8 * sizeof(int), stream);

    // --- one-time conversions / tables ---
    build_table<<<104, 256, 0, stream>>>(Wec, Wihc, bihc, bhhc, table);
    build_Wt<<<128, 256, 0, stream>>>(Whhc, Wt);
    conv_bf16<<<2560, 256, 0, stream>>>(Wih, Wihb, 4096 * 1280 / 8);
    conv_bf16<<<32, 256, 0, stream>>>(Wtag, Wtagb, 64 * 1024 / 8);

    // --- char-level LSTM: ALL 12 steps in one kernel ---
    char_fused<<<128, 256, 0, stream>>>(char_idx, Wt, table, h_cb);

    // --- word input projection ---
    build_Xw<<<SLEN * 160 / 256, 256, 0, stream>>>(word_idx, Wemb, h_cb, Xw);
    gemm_bf16_bt<<<dim3(32, 32), 256, 0, stream>>>(
        Xw, Wihb, bih, bhh, precomp, SLEN, 4096, 1280);

    // --- sequential word-level LSTM recurrence (per-XCD redundant) ---
    word_rec<<<256, 256, 0, stream>>>(precomp, Whh, hs_b, hdata, hsum, xcd_ctr);

    // --- tag projection + log_softmax ---
    tag_mfma<<<32, 256, 0, stream>>>(
        (const unsigned short*)hs_b, Wtagb, btag, out);
}